// Round 1
// baseline (1797.162 us; speedup 1.0000x reference)
//
#include <hip/hip_runtime.h>
#include <math.h>

// ---------------------------------------------------------------------------
// VQ-VAE forward, fp32 baseline.
// Structure for all convs: lanes = spatial, 16 co accumulators/thread,
// weights transposed to [ci][ky][kx][co] so weight reads are wave-uniform
// (scalar loads), input tiles staged in LDS with padded stride.
// ---------------------------------------------------------------------------

static __device__ __forceinline__ int rfl(int x) { return __builtin_amdgcn_readfirstlane(x); }

// ---------- weight prep ----------
// std conv w[co][ci][kh][kw] -> wT[(ci*KH*KW + k)*CO + co]
__global__ void k_transpose_w(const float* __restrict__ w, float* __restrict__ wT, int CO, int CIKK) {
  int idx = blockIdx.x * 256 + threadIdx.x;
  if (idx >= CO * CIKK) return;
  int co = idx % CO, i = idx / CO;
  wT[idx] = w[co * CIKK + i];
}

// convtranspose w[ci][co][kh][kw] -> wT[(ci*16 + k)*CO + co]
__global__ void k_transpose_wt(const float* __restrict__ w, float* __restrict__ wT, int CI, int CO) {
  int idx = blockIdx.x * 256 + threadIdx.x;
  if (idx >= CI * CO * 16) return;
  int co = idx % CO; int t = idx / CO; int k = t % 16; int ci = t / 16;
  wT[idx] = w[(ci * CO + co) * 16 + k];
}

// codebook [512][64] -> cbT [64][512], plus cnorm[j] = sum_c cb[j][c]^2
__global__ void k_prep_cb(const float* __restrict__ cb, float* __restrict__ cbT, float* __restrict__ cnorm) {
  int idx = blockIdx.x * 256 + threadIdx.x;
  if (idx < 512 * 64) {
    int j = idx / 64, c = idx % 64;
    cbT[c * 512 + j] = cb[idx];
  }
  if (idx < 512) {
    float s = 0.f;
    for (int c = 0; c < 64; ++c) { float v = cb[idx * 64 + c]; s = fmaf(v, v, s); }
    cnorm[idx] = s;
  }
}

// ---------- conv 4x4 stride2 pad1, CO=256, relu out ----------
// block: 8x8 out tile x 64 co (4 waves x 16 co accums); grid (tiles, CO/64, n)
__global__ __launch_bounds__(256) void k_conv4x4s2(
    const float* __restrict__ in, float* __restrict__ out,
    const float* __restrict__ wT, const float* __restrict__ bias,
    int CI, int IH, int IW, int OH, int OW)
{
  __shared__ float s_in[16 * 18 * 19];  // ci-chunk x 18 rows x stride-19 cols
  const int tid = threadIdx.x;
  const int lane = tid & 63;
  const int wv = rfl(tid >> 6);
  const int px = lane & 7, py = lane >> 3;
  const int ntx = OW >> 3;
  const int tx = blockIdx.x % ntx, ty = blockIdx.x / ntx;
  const int X = tx * 8, Y = ty * 8;
  const int cob = blockIdx.y * 64 + wv * 16;
  const int n = blockIdx.z;
  float acc[16];
#pragma unroll
  for (int i = 0; i < 16; ++i) acc[i] = bias[cob + i];
  const float* inN = in + (size_t)n * CI * IH * IW;
  for (int c0 = 0; c0 < CI; c0 += 16) {
    const int cc = min(16, CI - c0);
    for (int e = tid; e < cc * 342; e += 256) {
      int col = e % 19; int t = e / 19; int row = t % 18; int ci = t / 18 + c0;
      int iy = 2 * Y - 1 + row, ix = 2 * X - 1 + col;
      float v = 0.f;
      if (col < 18 && iy >= 0 && iy < IH && ix >= 0 && ix < IW)
        v = inN[(size_t)ci * IH * IW + (size_t)iy * IW + ix];
      s_in[e] = v;
    }
    __syncthreads();
    const float* wc = wT + (size_t)c0 * 16 * 256 + cob;
    for (int c = 0; c < cc; ++c) {
      const float* srow = s_in + c * 342 + py * 38 + px * 2;
#pragma unroll
      for (int ky = 0; ky < 4; ++ky) {
#pragma unroll
        for (int kx = 0; kx < 4; ++kx) {
          float iv = srow[ky * 19 + kx];
          const float* w = wc + (size_t)(c * 16 + ky * 4 + kx) * 256;  // uniform
#pragma unroll
          for (int i = 0; i < 16; ++i) acc[i] = fmaf(iv, w[i], acc[i]);
        }
      }
    }
    __syncthreads();
  }
  float* outN = out + ((size_t)n * 256 + cob) * OH * OW + (size_t)(Y + py) * OW + (X + px);
#pragma unroll
  for (int i = 0; i < 16; ++i) outN[(size_t)i * OH * OW] = fmaxf(acc[i], 0.f);
}

// ---------- conv 3x3 pad1, 256->256 @32x32, relu on INPUT, bias, raw out ----------
__global__ __launch_bounds__(256) void k_conv3x3(
    const float* __restrict__ in, float* __restrict__ out,
    const float* __restrict__ wT, const float* __restrict__ bias)
{
  __shared__ float s_in[16 * 110];  // 16 ci x 10 rows x stride-11
  const int tid = threadIdx.x;
  const int lane = tid & 63;
  const int wv = rfl(tid >> 6);
  const int px = lane & 7, py = lane >> 3;
  const int tx = blockIdx.x & 3, ty = blockIdx.x >> 2;
  const int X = tx * 8, Y = ty * 8;
  const int cob = blockIdx.y * 64 + wv * 16;
  const int n = blockIdx.z;
  float acc[16];
#pragma unroll
  for (int i = 0; i < 16; ++i) acc[i] = bias[cob + i];
  const float* inN = in + (size_t)n * 256 * 1024;
  for (int c0 = 0; c0 < 256; c0 += 16) {
    for (int e = tid; e < 16 * 110; e += 256) {
      int col = e % 11; int t = e / 11; int row = t % 10; int ci = t / 10 + c0;
      int iy = Y - 1 + row, ix = X - 1 + col;
      float v = 0.f;
      if (col < 10 && iy >= 0 && iy < 32 && ix >= 0 && ix < 32)
        v = fmaxf(inN[(size_t)ci * 1024 + iy * 32 + ix], 0.f);  // relu on input
      s_in[e] = v;
    }
    __syncthreads();
    const float* wc = wT + (size_t)c0 * 9 * 256 + cob;
    for (int c = 0; c < 16; ++c) {
      const float* srow = s_in + c * 110 + py * 11 + px;
#pragma unroll
      for (int ky = 0; ky < 3; ++ky) {
#pragma unroll
        for (int kx = 0; kx < 3; ++kx) {
          float iv = srow[ky * 11 + kx];
          const float* w = wc + (size_t)(c * 9 + ky * 3 + kx) * 256;  // uniform
#pragma unroll
          for (int i = 0; i < 16; ++i) acc[i] = fmaf(iv, w[i], acc[i]);
        }
      }
    }
    __syncthreads();
  }
  float* outN = out + ((size_t)n * 256 + cob) * 1024 + (size_t)(Y + py) * 32 + (X + px);
#pragma unroll
  for (int i = 0; i < 16; ++i) outN[(size_t)i * 1024] = acc[i];
}

// ---------- 1x1 conv / GEMM ----------
template<bool RELU_IN, bool RELU_OUT, bool ADD_OUT, bool HAS_BIAS>
__global__ __launch_bounds__(256) void k_conv1x1(
    const float* __restrict__ in, float* __restrict__ out,
    const float* __restrict__ wT, const float* __restrict__ bias,
    int CI, int CO, int P)
{
  const int p = blockIdx.x * 256 + threadIdx.x;
  const int cob = blockIdx.y * 16;
  const int n = blockIdx.z;
  const float* inN = in + (size_t)n * CI * P + p;
  float acc[16];
#pragma unroll
  for (int i = 0; i < 16; ++i) acc[i] = HAS_BIAS ? bias[cob + i] : 0.f;
  const float* wr = wT + cob;
#pragma unroll 4
  for (int ci = 0; ci < CI; ++ci) {
    float iv = inN[(size_t)ci * P];
    if (RELU_IN) iv = fmaxf(iv, 0.f);
    const float* w = wr + (size_t)ci * CO;  // uniform
#pragma unroll
    for (int i = 0; i < 16; ++i) acc[i] = fmaf(iv, w[i], acc[i]);
  }
  float* outN = out + (size_t)n * CO * P + p;
#pragma unroll
  for (int i = 0; i < 16; ++i) {
    float v = acc[i];
    if (RELU_OUT) v = fmaxf(v, 0.f);
    size_t o = (size_t)(cob + i) * P;
    if (ADD_OUT) outN[o] += v; else outN[o] = v;
  }
}

// ---------- argmin over codes ----------
__global__ void k_argmin(const float* __restrict__ dots, const float* __restrict__ cnorm,
                         int* __restrict__ ids, float* __restrict__ ids_f)
{
  int g = blockIdx.x * 256 + threadIdx.x;  // 8192 points
  int n = g >> 10, p = g & 1023;
  const float* dn = dots + (size_t)n * 512 * 1024 + p;
  float best = 3.4e38f; int bid = 0;
#pragma unroll 4
  for (int j = 0; j < 512; ++j) {
    float d = fmaf(-2.f, dn[(size_t)j * 1024], cnorm[j]);
    if (d < best) { best = d; bid = j; }  // strict <: keeps first min (np.argmin)
  }
  ids[g] = bid;
  ids_f[g] = (float)bid;
}

// ---------- e_k gather ----------
__global__ void k_gather_ek(const float* __restrict__ cb, const int* __restrict__ ids,
                            float* __restrict__ ek)
{
  int idx = blockIdx.x * 256 + threadIdx.x;  // 8*64*1024
  int p = idx & 1023; int c = (idx >> 10) & 63; int n = idx >> 16;
  int id = ids[(n << 10) + p];
  ek[idx] = cb[id * 64 + c];
}

// ---------- convtranspose 4x4 s2 p1, 256->256, relu out ----------
// 16x16 out tile; 4 waves = 4 output parity classes -> tap set wave-uniform.
__global__ __launch_bounds__(256) void k_tconv4x4_256(
    const float* __restrict__ in, float* __restrict__ out,
    const float* __restrict__ wT, const float* __restrict__ bias,
    int IH, int IW, int OH, int OW)
{
  __shared__ float s_in[16 * 110];
  const int tid = threadIdx.x;
  const int lane = tid & 63;
  const int wv = rfl(tid >> 6);
  const int ry = wv & 1, rx = (wv >> 1) & 1;
  const int lx = lane & 7, ly = lane >> 3;
  const int ntx = OW >> 4;
  const int tx = blockIdx.x % ntx, ty = blockIdx.x / ntx;
  const int X = tx * 16, Y = ty * 16;
  const int cob = blockIdx.y * 16;
  const int n = blockIdx.z;
  const int k0y = (ry + 1) & 1, k0x = (rx + 1) & 1;
  const int iy0 = (Y >> 1) - 1, ix0 = (X >> 1) - 1;
  float acc[16];
#pragma unroll
  for (int i = 0; i < 16; ++i) acc[i] = bias[cob + i];
  const float* inN = in + (size_t)n * 256 * IH * IW;
  for (int c0 = 0; c0 < 256; c0 += 16) {
    for (int e = tid; e < 16 * 110; e += 256) {
      int col = e % 11; int t = e / 11; int row = t % 10; int ci = t / 10 + c0;
      int iy = iy0 + row, ix = ix0 + col;
      float v = 0.f;
      if (col < 10 && iy >= 0 && iy < IH && ix >= 0 && ix < IW)
        v = inN[(size_t)ci * IH * IW + (size_t)iy * IW + ix];
      s_in[e] = v;
    }
    __syncthreads();
    for (int c = 0; c < 16; ++c) {
      const float* sc = s_in + c * 110 + (ly + ry + 1) * 11 + (lx + rx + 1);
#pragma unroll
      for (int a = 0; a < 2; ++a) {
#pragma unroll
        for (int b = 0; b < 2; ++b) {
          float iv = sc[-a * 11 - b];
          const int ky = k0y + 2 * a, kx = k0x + 2 * b;  // wave-uniform
          const float* w = wT + (size_t)((c0 + c) * 16 + ky * 4 + kx) * 256 + cob;
#pragma unroll
          for (int i = 0; i < 16; ++i) acc[i] = fmaf(iv, w[i], acc[i]);
        }
      }
    }
    __syncthreads();
  }
  const int oy = Y + 2 * ly + ry, ox = X + 2 * lx + rx;
  float* outN = out + ((size_t)n * 256 + cob) * OH * OW + (size_t)oy * OW + ox;
#pragma unroll
  for (int i = 0; i < 16; ++i) outN[(size_t)i * OH * OW] = fmaxf(acc[i], 0.f);
}

// ---------- convtranspose 4x4 s2 p1, 256->3, sigmoid ----------
__global__ __launch_bounds__(256) void k_tconv4x4_3(
    const float* __restrict__ in, float* __restrict__ out,
    const float* __restrict__ wT, const float* __restrict__ bias)
{
  __shared__ float s_in[16 * 110];
  const int tid = threadIdx.x;
  const int lane = tid & 63;
  const int wv = rfl(tid >> 6);
  const int ry = wv & 1, rx = (wv >> 1) & 1;
  const int lx = lane & 7, ly = lane >> 3;
  const int tx = blockIdx.x & 7, ty = blockIdx.x >> 3;
  const int X = tx * 16, Y = ty * 16;
  const int n = blockIdx.z;
  const int k0y = (ry + 1) & 1, k0x = (rx + 1) & 1;
  const int iy0 = (Y >> 1) - 1, ix0 = (X >> 1) - 1;
  float acc[3] = {bias[0], bias[1], bias[2]};
  const float* inN = in + (size_t)n * 256 * 4096;
  for (int c0 = 0; c0 < 256; c0 += 16) {
    for (int e = tid; e < 16 * 110; e += 256) {
      int col = e % 11; int t = e / 11; int row = t % 10; int ci = t / 10 + c0;
      int iy = iy0 + row, ix = ix0 + col;
      float v = 0.f;
      if (col < 10 && iy >= 0 && iy < 64 && ix >= 0 && ix < 64)
        v = inN[(size_t)ci * 4096 + iy * 64 + ix];
      s_in[e] = v;
    }
    __syncthreads();
    for (int c = 0; c < 16; ++c) {
      const float* sc = s_in + c * 110 + (ly + ry + 1) * 11 + (lx + rx + 1);
#pragma unroll
      for (int a = 0; a < 2; ++a) {
#pragma unroll
        for (int b = 0; b < 2; ++b) {
          float iv = sc[-a * 11 - b];
          const int ky = k0y + 2 * a, kx = k0x + 2 * b;
          const float* w = wT + (size_t)((c0 + c) * 16 + ky * 4 + kx) * 3;
#pragma unroll
          for (int i = 0; i < 3; ++i) acc[i] = fmaf(iv, w[i], acc[i]);
        }
      }
    }
    __syncthreads();
  }
  const int oy = Y + 2 * ly + ry, ox = X + 2 * lx + rx;
  float* outN = out + (size_t)n * 3 * 16384 + (size_t)oy * 128 + ox;
#pragma unroll
  for (int i = 0; i < 3; ++i) outN[(size_t)i * 16384] = 1.f / (1.f + expf(-acc[i]));
}

// ---------------------------------------------------------------------------
extern "C" void kernel_launch(void* const* d_in, const int* in_sizes, int n_in,
                              void* d_out, int out_size, void* d_ws, size_t ws_size,
                              hipStream_t stream) {
  (void)in_sizes; (void)n_in; (void)out_size; (void)ws_size;
  const float* x      = (const float*)d_in[0];
  const float* c1_w   = (const float*)d_in[1];
  const float* c1_b   = (const float*)d_in[2];
  const float* c2_w   = (const float*)d_in[3];
  const float* c2_b   = (const float*)d_in[4];
  const float* r0_w3  = (const float*)d_in[5];
  const float* r0_b3  = (const float*)d_in[6];
  const float* r0_w1  = (const float*)d_in[7];
  const float* r0_b1  = (const float*)d_in[8];
  const float* r1_w3  = (const float*)d_in[9];
  const float* r1_b3  = (const float*)d_in[10];
  const float* r1_w1  = (const float*)d_in[11];
  const float* r1_b1  = (const float*)d_in[12];
  const float* to_z_w = (const float*)d_in[13];
  const float* to_z_b = (const float*)d_in[14];
  const float* cb     = (const float*)d_in[15];
  const float* from_z_w = (const float*)d_in[16];
  const float* from_z_b = (const float*)d_in[17];
  const float* t1_w   = (const float*)d_in[18];
  const float* t1_b   = (const float*)d_in[19];
  const float* t2_w   = (const float*)d_in[20];
  const float* t2_b   = (const float*)d_in[21];

  float* wsf = (float*)d_ws;
  float* h1      = wsf + 0;         // 8388608 floats: conv1 out; later t1 out; dots/ids overlap
  float* h2      = wsf + 8388608;   // 2097152
  float* rbuf    = wsf + 10485760;  // 2097152
  float* dbuf    = wsf + 12582912;  // 2097152
  float* wt_c1   = wsf + 14680064;  // 12288
  float* wt_c2   = wsf + 14692352;  // 1048576
  float* wt_r0w3 = wsf + 15740928;  // 589824
  float* wt_r1w3 = wsf + 16330752;  // 589824
  float* wt_r0w1 = wsf + 16920576;  // 65536
  float* wt_r1w1 = wsf + 16986112;  // 65536
  float* wt_toz  = wsf + 17051648;  // 16384
  float* wt_fromz= wsf + 17068032;  // 16384
  float* wt_t1   = wsf + 17084416;  // 1048576
  float* wt_t2   = wsf + 18132992;  // 12288
  float* cbT     = wsf + 18145280;  // 32768
  float* cnorm   = wsf + 18178048;  // 512
  // dots (8x512x1024) + ids overlap h1 region: h1 is dead between conv2 and t1.
  float* dots = h1;
  int*   ids  = (int*)(h1 + 4194304);

  float* out_img = (float*)d_out;        // 393216
  float* z_e_out = out_img + 393216;     // 524288
  float* e_k_out = z_e_out + 524288;     // 524288
  float* ids_out = e_k_out + 524288;     // 8192 (stored as float)

  // ---- weight prep ----
  k_transpose_w<<<48,   256, 0, stream>>>(c1_w,  wt_c1,  256, 48);
  k_transpose_w<<<4096, 256, 0, stream>>>(c2_w,  wt_c2,  256, 4096);
  k_transpose_w<<<2304, 256, 0, stream>>>(r0_w3, wt_r0w3, 256, 2304);
  k_transpose_w<<<2304, 256, 0, stream>>>(r1_w3, wt_r1w3, 256, 2304);
  k_transpose_w<<<256,  256, 0, stream>>>(r0_w1, wt_r0w1, 256, 256);
  k_transpose_w<<<256,  256, 0, stream>>>(r1_w1, wt_r1w1, 256, 256);
  k_transpose_w<<<64,   256, 0, stream>>>(to_z_w, wt_toz, 64, 256);
  k_transpose_w<<<64,   256, 0, stream>>>(from_z_w, wt_fromz, 256, 64);
  k_transpose_wt<<<4096, 256, 0, stream>>>(t1_w, wt_t1, 256, 256);
  k_transpose_wt<<<48,   256, 0, stream>>>(t2_w, wt_t2, 256, 3);
  k_prep_cb<<<128, 256, 0, stream>>>(cb, cbT, cnorm);

  // ---- encoder ----
  k_conv4x4s2<<<dim3(64, 4, 8), 256, 0, stream>>>(x,  h1, wt_c1, c1_b, 3,   128, 128, 64, 64);
  k_conv4x4s2<<<dim3(16, 4, 8), 256, 0, stream>>>(h1, h2, wt_c2, c2_b, 256, 64,  64,  32, 32);
  k_conv3x3<<<dim3(16, 4, 8), 256, 0, stream>>>(h2, rbuf, wt_r0w3, r0_b3);
  k_conv1x1<true,  false, true,  true ><<<dim3(4, 16, 8), 256, 0, stream>>>(rbuf, h2, wt_r0w1, r0_b1, 256, 256, 1024);
  k_conv3x3<<<dim3(16, 4, 8), 256, 0, stream>>>(h2, rbuf, wt_r1w3, r1_b3);
  k_conv1x1<true,  false, true,  true ><<<dim3(4, 16, 8), 256, 0, stream>>>(rbuf, h2, wt_r1w1, r1_b1, 256, 256, 1024);
  k_conv1x1<false, false, false, true ><<<dim3(4, 4, 8),  256, 0, stream>>>(h2, z_e_out, wt_toz, to_z_b, 256, 64, 1024);

  // ---- VQ ----
  k_conv1x1<false, false, false, false><<<dim3(4, 32, 8), 256, 0, stream>>>(z_e_out, dots, cbT, nullptr, 64, 512, 1024);
  k_argmin<<<32, 256, 0, stream>>>(dots, cnorm, ids, ids_out);
  k_gather_ek<<<2048, 256, 0, stream>>>(cb, ids, e_k_out);

  // ---- decoder ----
  k_conv1x1<false, true,  false, true ><<<dim3(4, 16, 8), 256, 0, stream>>>(e_k_out, dbuf, wt_fromz, from_z_b, 64, 256, 1024);
  k_tconv4x4_256<<<dim3(16, 16, 8), 256, 0, stream>>>(dbuf, h1, wt_t1, t1_b, 32, 32, 64, 64);
  k_tconv4x4_3<<<dim3(64, 1, 8), 256, 0, stream>>>(h1, out_img, wt_t2, t2_b);
}

// Round 2
// 1555.040 us; speedup vs baseline: 1.1557x; 1.1557x over previous
//
#include <hip/hip_runtime.h>
#include <math.h>

// ---------------------------------------------------------------------------
// VQ-VAE forward. Encoder fp32 (ids must be exact); decoder t1 in bf16 MFMA.
// fp32 convs: lanes = spatial, 16 co accums/thread, wave-uniform weight reads,
// LDS layouts chosen for <=2-way bank aliasing (free on CDNA4).
// ---------------------------------------------------------------------------

typedef unsigned int uint;
typedef unsigned short ushort_t;
using short8 = __attribute__((ext_vector_type(8))) short;
using f32x4  = __attribute__((ext_vector_type(4))) float;

static __device__ __forceinline__ int rfl(int x) { return __builtin_amdgcn_readfirstlane(x); }
static __device__ __forceinline__ ushort_t f2bf(float f) {
  uint u = __float_as_uint(f);
  uint r = (u + 0x7fffu + ((u >> 16) & 1u)) >> 16;  // RNE; inputs finite
  return (ushort_t)r;
}

// ---------- weight prep ----------
// std conv w[co][ci][kh][kw] -> wT[(ci*KH*KW + k)*CO + co]
__global__ void k_transpose_w(const float* __restrict__ w, float* __restrict__ wT, int CO, int CIKK) {
  int idx = blockIdx.x * 256 + threadIdx.x;
  if (idx >= CO * CIKK) return;
  int co = idx % CO, i = idx / CO;
  wT[idx] = w[co * CIKK + i];
}

// convtranspose w[ci][co][kh][kw] -> wT[(ci*16 + k)*CO + co]  (used for t2 only)
__global__ void k_transpose_wt(const float* __restrict__ w, float* __restrict__ wT, int CI, int CO) {
  int idx = blockIdx.x * 256 + threadIdx.x;
  if (idx >= CI * CO * 16) return;
  int co = idx % CO; int t = idx / CO; int k = t % 16; int ci = t / 16;
  wT[idx] = w[(ci * CO + co) * 16 + k];
}

// t1_w [ci][co][ky][kx] -> bf16 [par][tap][c8][co][kk32]
__global__ void k_prep_t1w(const float* __restrict__ w, ushort_t* __restrict__ wb) {
  int idx = blockIdx.x * 256 + threadIdx.x;  // 1048576
  int kk  = idx & 31;
  int co  = (idx >> 5) & 255;
  int c8  = (idx >> 13) & 7;
  int tap = (idx >> 16) & 3;
  int par = idx >> 18;
  int ry = par & 1, rx = (par >> 1) & 1;
  int a = tap >> 1, b = tap & 1;
  int ky = ((ry + 1) & 1) + 2 * a;
  int kx = ((rx + 1) & 1) + 2 * b;
  int ci = c8 * 32 + kk;
  wb[idx] = f2bf(w[((ci * 256 + co) << 4) + ky * 4 + kx]);
}

// cnorm[j] = sum_c cb[j][c]^2
__global__ void k_prep_cb(const float* __restrict__ cb, float* __restrict__ cnorm) {
  int idx = blockIdx.x * 256 + threadIdx.x;
  if (idx < 512) {
    float s = 0.f;
    for (int c = 0; c < 64; ++c) { float v = cb[idx * 64 + c]; s = fmaf(v, v, s); }
    cnorm[idx] = s;
  }
}

// ---------- conv 4x4 stride2 pad1, CO=256, relu out ----------
// LDS: column-parity-split storage, row pitch 20 -> exact 2-way banks (free).
__global__ __launch_bounds__(256) void k_conv4x4s2(
    const float* __restrict__ in, float* __restrict__ out,
    const float* __restrict__ wT, const float* __restrict__ bias,
    int CI, int IH, int IW, int OH, int OW)
{
  __shared__ float s_in[16 * 360];  // ci x 18 rows x [parity*10 + halfcol] pitch 20
  const int tid = threadIdx.x;
  const int lane = tid & 63;
  const int wv = rfl(tid >> 6);
  const int px = lane & 7, py = lane >> 3;
  const int ntx = OW >> 3;
  const int tx = blockIdx.x % ntx, ty = blockIdx.x / ntx;
  const int X = tx * 8, Y = ty * 8;
  const int cob = blockIdx.y * 64 + wv * 16;
  const int n = blockIdx.z;
  float acc[16];
#pragma unroll
  for (int i = 0; i < 16; ++i) acc[i] = bias[cob + i];
  const float* inN = in + (size_t)n * CI * IH * IW;
  for (int c0 = 0; c0 < CI; c0 += 16) {
    const int cc = min(16, CI - c0);
    for (int e = tid; e < cc * 360; e += 256) {
      int col2 = e % 20; int t = e / 20; int row = t % 18; int ci = t / 18 + c0;
      int pr = col2 / 10, hc = col2 % 10;
      int ixl = 2 * hc + pr;
      int iy = 2 * Y - 1 + row, ix = 2 * X - 1 + ixl;
      float v = 0.f;
      if (ixl < 18 && iy >= 0 && iy < IH && ix >= 0 && ix < IW)
        v = inN[(size_t)ci * IH * IW + (size_t)iy * IW + ix];
      s_in[e] = v;
    }
    __syncthreads();
    const float* wc = wT + (size_t)c0 * 16 * 256 + cob;
    for (int c = 0; c < cc; ++c) {
      const float* base = s_in + c * 360 + py * 40 + px;
#pragma unroll
      for (int ky = 0; ky < 4; ++ky) {
#pragma unroll
        for (int kx = 0; kx < 4; ++kx) {
          float iv = base[ky * 20 + (kx & 1) * 10 + (kx >> 1)];
          const float* w = wc + (size_t)(c * 16 + ky * 4 + kx) * 256;  // uniform
#pragma unroll
          for (int i = 0; i < 16; ++i) acc[i] = fmaf(iv, w[i], acc[i]);
        }
      }
    }
    __syncthreads();
  }
  float* outN = out + ((size_t)n * 256 + cob) * OH * OW + (size_t)(Y + py) * OW + (X + px);
#pragma unroll
  for (int i = 0; i < 16; ++i) outN[(size_t)i * OH * OW] = fmaxf(acc[i], 0.f);
}

// ---------- conv 3x3 pad1, 256->256 @32x32, relu on INPUT ----------
__global__ __launch_bounds__(256) void k_conv3x3(
    const float* __restrict__ in, float* __restrict__ out,
    const float* __restrict__ wT, const float* __restrict__ bias)
{
  __shared__ float s_in[16 * 120];  // 16 ci x 10 rows x pitch 12 (2-way free)
  const int tid = threadIdx.x;
  const int lane = tid & 63;
  const int wv = rfl(tid >> 6);
  const int px = lane & 7, py = lane >> 3;
  const int tx = blockIdx.x & 3, ty = blockIdx.x >> 2;
  const int X = tx * 8, Y = ty * 8;
  const int cob = blockIdx.y * 64 + wv * 16;
  const int n = blockIdx.z;
  float acc[16];
#pragma unroll
  for (int i = 0; i < 16; ++i) acc[i] = bias[cob + i];
  const float* inN = in + (size_t)n * 256 * 1024;
  for (int c0 = 0; c0 < 256; c0 += 16) {
    for (int e = tid; e < 16 * 120; e += 256) {
      int col = e % 12; int t = e / 12; int row = t % 10; int ci = t / 10 + c0;
      int iy = Y - 1 + row, ix = X - 1 + col;
      float v = 0.f;
      if (col < 10 && iy >= 0 && iy < 32 && ix >= 0 && ix < 32)
        v = fmaxf(inN[(size_t)ci * 1024 + iy * 32 + ix], 0.f);
      s_in[e] = v;
    }
    __syncthreads();
    const float* wc = wT + (size_t)c0 * 9 * 256 + cob;
    for (int c = 0; c < 16; ++c) {
      const float* srow = s_in + c * 120 + py * 12 + px;
#pragma unroll
      for (int ky = 0; ky < 3; ++ky) {
#pragma unroll
        for (int kx = 0; kx < 3; ++kx) {
          float iv = srow[ky * 12 + kx];
          const float* w = wc + (size_t)(c * 9 + ky * 3 + kx) * 256;  // uniform
#pragma unroll
          for (int i = 0; i < 16; ++i) acc[i] = fmaf(iv, w[i], acc[i]);
        }
      }
    }
    __syncthreads();
  }
  float* outN = out + ((size_t)n * 256 + cob) * 1024 + (size_t)(Y + py) * 32 + (X + px);
#pragma unroll
  for (int i = 0; i < 16; ++i) outN[(size_t)i * 1024] = acc[i];
}

// ---------- 1x1 conv / GEMM (fp32) ----------
template<bool RELU_IN, bool RELU_OUT, bool ADD_OUT, bool HAS_BIAS>
__global__ __launch_bounds__(256) void k_conv1x1(
    const float* __restrict__ in, float* __restrict__ out,
    const float* __restrict__ wT, const float* __restrict__ bias,
    int CI, int CO, int P)
{
  const int p = blockIdx.x * 256 + threadIdx.x;
  const int cob = blockIdx.y * 16;
  const int n = blockIdx.z;
  const float* inN = in + (size_t)n * CI * P + p;
  float acc[16];
#pragma unroll
  for (int i = 0; i < 16; ++i) acc[i] = HAS_BIAS ? bias[cob + i] : 0.f;
  const float* wr = wT + cob;
#pragma unroll 4
  for (int ci = 0; ci < CI; ++ci) {
    float iv = inN[(size_t)ci * P];
    if (RELU_IN) iv = fmaxf(iv, 0.f);
    const float* w = wr + (size_t)ci * CO;  // uniform
#pragma unroll
    for (int i = 0; i < 16; ++i) acc[i] = fmaf(iv, w[i], acc[i]);
  }
  float* outN = out + (size_t)n * CO * P + p;
#pragma unroll
  for (int i = 0; i < 16; ++i) {
    float v = acc[i];
    if (RELU_OUT) v = fmaxf(v, 0.f);
    size_t o = (size_t)(cob + i) * P;
    if (ADD_OUT) outN[o] += v; else outN[o] = v;
  }
}

// ---------- fused VQ: dots + argmin + ids + e_k gather ----------
__global__ __launch_bounds__(256) void k_vq(
    const float* __restrict__ z_e, const float* __restrict__ cb,
    const float* __restrict__ cnorm, float* __restrict__ ids_f,
    float* __restrict__ ek)
{
  int g = blockIdx.x * 256 + threadIdx.x;  // 8192 points
  int img = g >> 10, p = g & 1023;
  const float* zp = z_e + (size_t)img * 64 * 1024 + p;
  float z[64];
#pragma unroll
  for (int c = 0; c < 64; ++c) z[c] = zp[(size_t)c * 1024];
  float best = 3.4e38f; int bid = 0;
  for (int j = 0; j < 512; ++j) {
    const float* cj = cb + j * 64;  // uniform -> scalar loads
    float m = 0.f;
#pragma unroll
    for (int c = 0; c < 64; ++c) m = fmaf(z[c], cj[c], m);
    float d = fmaf(-2.f, m, cnorm[j]);
    if (d < best) { best = d; bid = j; }  // strict <: first-min (np.argmin)
  }
  ids_f[g] = (float)bid;
  const float* cbid = cb + bid * 64;
  float* ekp = ek + (size_t)img * 64 * 1024 + p;
#pragma unroll
  for (int c = 0; c < 64; ++c) ekp[(size_t)c * 1024] = cbid[c];
}

// ---------- from_z 1x1 (64->256) + relu, output NHWC bf16 for t1-MFMA ----------
__global__ __launch_bounds__(256) void k_from_z(
    const float* __restrict__ ek, ushort_t* __restrict__ nhwc,
    const float* __restrict__ wT, const float* __restrict__ bias)
{
  const int p = blockIdx.x * 256 + threadIdx.x;  // 0..1023
  const int co0 = blockIdx.y * 16;
  const int n = blockIdx.z;
  const float* inN = ek + (size_t)n * 64 * 1024 + p;
  float acc[16];
#pragma unroll
  for (int i = 0; i < 16; ++i) acc[i] = bias[co0 + i];
#pragma unroll 4
  for (int ci = 0; ci < 64; ++ci) {
    float iv = inN[(size_t)ci * 1024];
    const float* w = wT + (size_t)ci * 256 + co0;  // uniform
#pragma unroll
    for (int i = 0; i < 16; ++i) acc[i] = fmaf(iv, w[i], acc[i]);
  }
  uint pk[8];
#pragma unroll
  for (int i = 0; i < 8; ++i) {
    ushort_t lo = f2bf(fmaxf(acc[2 * i], 0.f));
    ushort_t hi = f2bf(fmaxf(acc[2 * i + 1], 0.f));
    pk[i] = (uint)lo | ((uint)hi << 16);
  }
  ushort_t* op = nhwc + (((size_t)n * 1024 + p) * 256 + co0);
  uint4 v0; v0.x = pk[0]; v0.y = pk[1]; v0.z = pk[2]; v0.w = pk[3];
  uint4 v1; v1.x = pk[4]; v1.y = pk[5]; v1.z = pk[6]; v1.w = pk[7];
  *(uint4*)(op) = v0;
  *(uint4*)(op + 8) = v1;
}

// ---------- t1 convtranspose 4x4 s2 p1, 256->256, bf16 MFMA, relu, fp32 NCHW out
// Per parity class: D[co][px] = sum_k W[k][co] * In[k][px], K = 4 taps x 256 ci.
// Block: 128co x 128px, 4 waves of 64x64 (4x4 of 16x16x32 MFMA tiles).
__global__ __launch_bounds__(256) void k_mfma_t1(
    const ushort_t* __restrict__ nhwc, const ushort_t* __restrict__ wb,
    const float* __restrict__ bias, float* __restrict__ out)
{
  __shared__ ushort_t sA[128 * 32];  // [co][kk] pitch 64B -> b128 conflict-free
  __shared__ ushort_t sB[128 * 32];  // [px][kk]
  const int tid = threadIdx.x;
  const int lane = tid & 63;
  const int wv = tid >> 6;
  const int wm = wv & 1, wn = wv >> 1;
  const int l15 = lane & 15, q = lane >> 4;
  const int pxT = blockIdx.x, coT = blockIdx.y, par = blockIdx.z;
  const int ry = par & 1, rx = (par >> 1) & 1;
  const int pxbase = pxT * 128;
  const int img = pxbase >> 10;
  f32x4 acc[4][4];
#pragma unroll
  for (int i = 0; i < 4; ++i)
#pragma unroll
    for (int j = 0; j < 4; ++j) acc[i][j] = (f32x4){0.f, 0.f, 0.f, 0.f};

  for (int c = 0; c < 32; ++c) {
    const int tap = c >> 3, c8 = c & 7;
    const int a = tap >> 1, b = tap & 1;
    const ushort_t* Abase = wb + ((size_t)((par * 4 + tap) * 8 + c8) << 13);  // *8192
#pragma unroll
    for (int r = 0; r < 2; ++r) {
      int idx = tid + 256 * r;
      int row = idx >> 2, kg = idx & 3;
      uint4 v = *(const uint4*)(Abase + ((coT * 128 + row) * 32 + kg * 8));
      *(uint4*)(&sA[row * 32 + kg * 8]) = v;
    }
#pragma unroll
    for (int r = 0; r < 2; ++r) {
      int idx = tid + 256 * r;
      int row = idx >> 2, kg = idx & 3;
      int px = pxbase + row;
      int u = (px >> 5) & 31, vv = px & 31;
      int iy = u + ry - a, ix = vv + rx - b;
      uint4 val;
      if ((unsigned)iy < 32u && (unsigned)ix < 32u) {
        val = *(const uint4*)(nhwc + ((size_t)(img * 1024 + iy * 32 + ix) * 256 + c8 * 32 + kg * 8));
      } else { val.x = 0u; val.y = 0u; val.z = 0u; val.w = 0u; }
      *(uint4*)(&sB[row * 32 + kg * 8]) = val;
    }
    __syncthreads();
    short8 af[4], bfr[4];
#pragma unroll
    for (int i = 0; i < 4; ++i)
      af[i] = *(const short8*)((const short*)sA + ((wm * 64 + i * 16 + l15) * 32 + q * 8));
#pragma unroll
    for (int j = 0; j < 4; ++j)
      bfr[j] = *(const short8*)((const short*)sB + ((wn * 64 + j * 16 + l15) * 32 + q * 8));
#pragma unroll
    for (int i = 0; i < 4; ++i)
#pragma unroll
      for (int j = 0; j < 4; ++j)
        acc[i][j] = __builtin_amdgcn_mfma_f32_16x16x32_bf16(af[i], bfr[j], acc[i][j], 0, 0, 0);
    __syncthreads();
  }
  // epilogue: D row m = co (q*4+reg), col n = px (l15)
#pragma unroll
  for (int i = 0; i < 4; ++i) {
    int co = coT * 128 + wm * 64 + i * 16 + q * 4;
#pragma unroll
    for (int j = 0; j < 4; ++j) {
      int px = pxbase + wn * 64 + j * 16 + l15;
      int u = (px >> 5) & 31, vv = px & 31;
      int oy = 2 * u + ry, ox = 2 * vv + rx;
      float* op = out + (size_t)img * 256 * 4096 + (size_t)oy * 64 + ox;
#pragma unroll
      for (int rg = 0; rg < 4; ++rg) {
        float val = acc[i][j][rg] + bias[co + rg];
        op[(size_t)(co + rg) * 4096] = fmaxf(val, 0.f);
      }
    }
  }
}

// ---------- convtranspose 4x4 s2 p1, 256->3, sigmoid (fp32) ----------
__global__ __launch_bounds__(256) void k_tconv4x4_3(
    const float* __restrict__ in, float* __restrict__ out,
    const float* __restrict__ wT, const float* __restrict__ bias)
{
  __shared__ float s_in[16 * 120];  // pitch 12
  const int tid = threadIdx.x;
  const int lane = tid & 63;
  const int wv = rfl(tid >> 6);
  const int ry = wv & 1, rx = (wv >> 1) & 1;
  const int lx = lane & 7, ly = lane >> 3;
  const int tx = blockIdx.x & 7, ty = blockIdx.x >> 3;
  const int X = tx * 16, Y = ty * 16;
  const int n = blockIdx.z;
  const int k0y = (ry + 1) & 1, k0x = (rx + 1) & 1;
  const int iy0 = (Y >> 1) - 1, ix0 = (X >> 1) - 1;
  float acc[3] = {bias[0], bias[1], bias[2]};
  const float* inN = in + (size_t)n * 256 * 4096;
  for (int c0 = 0; c0 < 256; c0 += 16) {
    for (int e = tid; e < 16 * 120; e += 256) {
      int col = e % 12; int t = e / 12; int row = t % 10; int ci = t / 10 + c0;
      int iy = iy0 + row, ix = ix0 + col;
      float v = 0.f;
      if (col < 10 && iy >= 0 && iy < 64 && ix >= 0 && ix < 64)
        v = inN[(size_t)ci * 4096 + iy * 64 + ix];
      s_in[e] = v;
    }
    __syncthreads();
    for (int c = 0; c < 16; ++c) {
      const float* sc = s_in + c * 120 + (ly + ry + 1) * 12 + (lx + rx + 1);
#pragma unroll
      for (int a = 0; a < 2; ++a) {
#pragma unroll
        for (int b = 0; b < 2; ++b) {
          float iv = sc[-a * 12 - b];
          const int ky = k0y + 2 * a, kx = k0x + 2 * b;
          const float* w = wT + (size_t)((c0 + c) * 16 + ky * 4 + kx) * 3;
#pragma unroll
          for (int i = 0; i < 3; ++i) acc[i] = fmaf(iv, w[i], acc[i]);
        }
      }
    }
    __syncthreads();
  }
  const int oy = Y + 2 * ly + ry, ox = X + 2 * lx + rx;
  float* outN = out + (size_t)n * 3 * 16384 + (size_t)oy * 128 + ox;
#pragma unroll
  for (int i = 0; i < 3; ++i) outN[(size_t)i * 16384] = 1.f / (1.f + expf(-acc[i]));
}

// ---------------------------------------------------------------------------
extern "C" void kernel_launch(void* const* d_in, const int* in_sizes, int n_in,
                              void* d_out, int out_size, void* d_ws, size_t ws_size,
                              hipStream_t stream) {
  (void)in_sizes; (void)n_in; (void)out_size; (void)ws_size;
  const float* x      = (const float*)d_in[0];
  const float* c1_w   = (const float*)d_in[1];
  const float* c1_b   = (const float*)d_in[2];
  const float* c2_w   = (const float*)d_in[3];
  const float* c2_b   = (const float*)d_in[4];
  const float* r0_w3  = (const float*)d_in[5];
  const float* r0_b3  = (const float*)d_in[6];
  const float* r0_w1  = (const float*)d_in[7];
  const float* r0_b1  = (const float*)d_in[8];
  const float* r1_w3  = (const float*)d_in[9];
  const float* r1_b3  = (const float*)d_in[10];
  const float* r1_w1  = (const float*)d_in[11];
  const float* r1_b1  = (const float*)d_in[12];
  const float* to_z_w = (const float*)d_in[13];
  const float* to_z_b = (const float*)d_in[14];
  const float* cb     = (const float*)d_in[15];
  const float* from_z_w = (const float*)d_in[16];
  const float* from_z_b = (const float*)d_in[17];
  const float* t1_w   = (const float*)d_in[18];
  const float* t1_b   = (const float*)d_in[19];
  const float* t2_w   = (const float*)d_in[20];
  const float* t2_b   = (const float*)d_in[21];

  float* wsf = (float*)d_ws;
  float*    h1      = wsf + 0;         // 8388608 (conv1 out; later t1 out)
  float*    h2      = wsf + 8388608;   // 2097152
  float*    rbuf    = wsf + 10485760;  // 2097152
  ushort_t* nhwc    = (ushort_t*)(wsf + 12582912);  // 2097152 bf16 = 1048576 floats
  float*    wt_c1   = wsf + 13631488;  // 12288
  float*    wt_c2   = wsf + 13643776;  // 1048576
  float*    wt_r0w3 = wsf + 14692352;  // 589824
  float*    wt_r1w3 = wsf + 15282176;  // 589824
  float*    wt_r0w1 = wsf + 15872000;  // 65536
  float*    wt_r1w1 = wsf + 15937536;  // 65536
  float*    wt_toz  = wsf + 16003072;  // 16384
  float*    wt_fromz= wsf + 16019456;  // 16384
  float*    wt_t2   = wsf + 16035840;  // 12288
  ushort_t* t1wb    = (ushort_t*)(wsf + 16048128);  // 1048576 bf16 = 524288 floats
  float*    cnorm   = wsf + 16572416;  // 512

  float* out_img = (float*)d_out;        // 393216
  float* z_e_out = out_img + 393216;     // 524288
  float* e_k_out = z_e_out + 524288;     // 524288
  float* ids_out = e_k_out + 524288;     // 8192 (stored as float)

  // ---- weight prep ----
  k_transpose_w<<<48,   256, 0, stream>>>(c1_w,  wt_c1,  256, 48);
  k_transpose_w<<<4096, 256, 0, stream>>>(c2_w,  wt_c2,  256, 4096);
  k_transpose_w<<<2304, 256, 0, stream>>>(r0_w3, wt_r0w3, 256, 2304);
  k_transpose_w<<<2304, 256, 0, stream>>>(r1_w3, wt_r1w3, 256, 2304);
  k_transpose_w<<<256,  256, 0, stream>>>(r0_w1, wt_r0w1, 256, 256);
  k_transpose_w<<<256,  256, 0, stream>>>(r1_w1, wt_r1w1, 256, 256);
  k_transpose_w<<<64,   256, 0, stream>>>(to_z_w, wt_toz, 64, 256);
  k_transpose_w<<<64,   256, 0, stream>>>(from_z_w, wt_fromz, 256, 64);
  k_transpose_wt<<<48,  256, 0, stream>>>(t2_w, wt_t2, 256, 3);
  k_prep_t1w<<<4096, 256, 0, stream>>>(t1_w, t1wb);
  k_prep_cb<<<2, 256, 0, stream>>>(cb, cnorm);

  // ---- encoder (fp32, feeds argmin -> must stay exact-ish) ----
  k_conv4x4s2<<<dim3(64, 4, 8), 256, 0, stream>>>(x,  h1, wt_c1, c1_b, 3,   128, 128, 64, 64);
  k_conv4x4s2<<<dim3(16, 4, 8), 256, 0, stream>>>(h1, h2, wt_c2, c2_b, 256, 64,  64,  32, 32);
  k_conv3x3<<<dim3(16, 4, 8), 256, 0, stream>>>(h2, rbuf, wt_r0w3, r0_b3);
  k_conv1x1<true,  false, true,  true ><<<dim3(4, 16, 8), 256, 0, stream>>>(rbuf, h2, wt_r0w1, r0_b1, 256, 256, 1024);
  k_conv3x3<<<dim3(16, 4, 8), 256, 0, stream>>>(h2, rbuf, wt_r1w3, r1_b3);
  k_conv1x1<true,  false, true,  true ><<<dim3(4, 16, 8), 256, 0, stream>>>(rbuf, h2, wt_r1w1, r1_b1, 256, 256, 1024);
  k_conv1x1<false, false, false, true ><<<dim3(4, 4, 8),  256, 0, stream>>>(h2, z_e_out, wt_toz, to_z_b, 256, 64, 1024);

  // ---- VQ (fused dots+argmin+ids+e_k) ----
  k_vq<<<32, 256, 0, stream>>>(z_e_out, cb, cnorm, ids_out, e_k_out);

  // ---- decoder (bf16 ok; only feeds sigmoid output) ----
  k_from_z<<<dim3(4, 16, 8), 256, 0, stream>>>(e_k_out, nhwc, wt_fromz, from_z_b);
  k_mfma_t1<<<dim3(64, 2, 4), 256, 0, stream>>>(nhwc, t1wb, t1_b, h1);
  k_tconv4x4_3<<<dim3(64, 1, 8), 256, 0, stream>>>(h1, out_img, wt_t2, t2_b);
}

// Round 3
// 757.501 us; speedup vs baseline: 2.3725x; 2.0529x over previous
//
#include <hip/hip_runtime.h>
#include <math.h>

// ---------------------------------------------------------------------------
// VQ-VAE forward.
// Encoder: 256-ch convs as implicit-GEMM MFMA with 2-term bf16 split inputs
// (3 passes: w1x1 + w1x2 + w2x1, rel err ~1e-5 -> ids stay exact).
// Residual spine h kept in fp32; activations as NHWC split-bf16 planes.
// Decoder: t1 + t2 in plain bf16 MFMA. VQ / to_z / conv1 in fp32.
// All MFMA uses the round-2-verified 16x16x32 fragment layouts.
// ---------------------------------------------------------------------------

typedef unsigned int uint;
typedef unsigned short ushort_t;
using short8 = __attribute__((ext_vector_type(8))) short;
using f32x4  = __attribute__((ext_vector_type(4))) float;

static __device__ __forceinline__ int rfl(int x) { return __builtin_amdgcn_readfirstlane(x); }
static __device__ __forceinline__ ushort_t f2bf(float f) {
  uint u = __float_as_uint(f);
  return (ushort_t)((u + 0x7fffu + ((u >> 16) & 1u)) >> 16);  // RNE; finite inputs
}
static __device__ __forceinline__ float bf2f(ushort_t b) {
  return __uint_as_float(((uint)b) << 16);
}

// ---------- weight prep ----------
// std conv w[co][ci][kh][kw] -> wT[(ci*KH*KW + k)*CO + co]  (fp32 kernels)
__global__ void k_transpose_w(const float* __restrict__ w, float* __restrict__ wT, int CO, int CIKK) {
  int idx = blockIdx.x * 256 + threadIdx.x;
  if (idx >= CO * CIKK) return;
  int co = idx % CO, i = idx / CO;
  wT[idx] = w[co * CIKK + i];
}

// encoder MFMA weight pack: w[co][ci(256)][KH][KW] fp32 ->
// wp[chunk][coT(4)][pl(2)][row(64)][k(32)] bf16 split, chunk = tap*8 + cg
template<int KIND>  // 0: 4x4 (16 taps), 1: 3x3 (9 taps), 2: 1x1 (1 tap)
__global__ void k_prep_enc(const float* __restrict__ w, ushort_t* __restrict__ wp, int total) {
  int idx = blockIdx.x * 256 + threadIdx.x;
  if (idx >= total) return;
  int k = idx & 31, row = (idx >> 5) & 63, pl = (idx >> 11) & 1, coT = (idx >> 12) & 3, chunk = idx >> 14;
  int tap = chunk >> 3, cg = chunk & 7;
  int co = coT * 64 + row, ci = cg * 32 + k;
  int ky, kx, KK, KW;
  if (KIND == 0)      { ky = tap >> 2; kx = tap & 3;       KK = 16; KW = 4; }
  else if (KIND == 1) { ky = tap / 3;  kx = tap - ky * 3;  KK = 9;  KW = 3; }
  else                { ky = 0;        kx = 0;             KK = 1;  KW = 1; }
  float v = w[(co * 256 + ci) * KK + ky * KW + kx];
  ushort_t b0 = f2bf(v);
  wp[idx] = pl ? f2bf(v - bf2f(b0)) : b0;
}

// t1_w [ci][co][ky][kx] -> bf16 [par][tap][c8][co][kk32]  (round-2, verified)
__global__ void k_prep_t1w(const float* __restrict__ w, ushort_t* __restrict__ wb) {
  int idx = blockIdx.x * 256 + threadIdx.x;  // 1048576
  int kk  = idx & 31;
  int co  = (idx >> 5) & 255;
  int c8  = (idx >> 13) & 7;
  int tap = (idx >> 16) & 3;
  int par = idx >> 18;
  int ry = par & 1, rx = (par >> 1) & 1;
  int a = tap >> 1, b = tap & 1;
  int ky = ((ry + 1) & 1) + 2 * a;
  int kx = ((rx + 1) & 1) + 2 * b;
  int ci = c8 * 32 + kk;
  wb[idx] = f2bf(w[((ci * 256 + co) << 4) + ky * 4 + kx]);
}

// t2_w [ci(256)][co(3)][4][4] -> bf16 [par(4)][chunk(32)][co16][k32]
__global__ void k_prep_t2w(const float* __restrict__ w, ushort_t* __restrict__ wb) {
  int idx = blockIdx.x * 256 + threadIdx.x;  // 65536
  int k = idx & 31, co = (idx >> 5) & 15, chunk = (idx >> 9) & 31, par = idx >> 14;
  int tap = chunk >> 3, cg = chunk & 7;
  int a = tap >> 1, b = tap & 1;
  int ry = par & 1, rx = (par >> 1) & 1;
  int ky = ((ry + 1) & 1) + 2 * a;
  int kx = ((rx + 1) & 1) + 2 * b;
  int ci = cg * 32 + k;
  float v = (co < 3) ? w[((ci * 3 + co) << 4) + ky * 4 + kx] : 0.f;
  wb[idx] = f2bf(v);
}

// cnorm[j] = sum_c cb[j][c]^2
__global__ void k_prep_cb(const float* __restrict__ cb, float* __restrict__ cnorm) {
  int idx = blockIdx.x * 256 + threadIdx.x;
  if (idx < 512) {
    float s = 0.f;
    for (int c = 0; c < 64; ++c) { float v = cb[idx * 64 + c]; s = fmaf(v, v, s); }
    cnorm[idx] = s;
  }
}

// ---------- conv1: 3->256, 4x4 s2 p1, relu, output split-bf16 NHWC ----------
__global__ __launch_bounds__(256) void k_conv1_split(
    const float* __restrict__ in, ushort_t* __restrict__ o0, ushort_t* __restrict__ o1,
    const float* __restrict__ wT, const float* __restrict__ bias)
{
  __shared__ float s_in[3 * 360];  // parity-split cols, pitch 20 (2-way free)
  const int tid = threadIdx.x;
  const int lane = tid & 63;
  const int wv = rfl(tid >> 6);
  const int px = lane & 7, py = lane >> 3;
  const int tx = blockIdx.x & 7, ty = blockIdx.x >> 3;
  const int X = tx * 8, Y = ty * 8;
  const int cob = blockIdx.y * 64 + wv * 16;
  const int n = blockIdx.z;
  float acc[16];
#pragma unroll
  for (int i = 0; i < 16; ++i) acc[i] = bias[cob + i];
  const float* inN = in + (size_t)n * 3 * 16384;
  for (int e = tid; e < 3 * 360; e += 256) {
    int col2 = e % 20; int t = e / 20; int row = t % 18; int ci = t / 18;
    int pr = col2 / 10, hc = col2 % 10, ixl = 2 * hc + pr;
    int iy = 2 * Y - 1 + row, ix = 2 * X - 1 + ixl;
    float v = 0.f;
    if (ixl < 18 && (unsigned)iy < 128u && (unsigned)ix < 128u)
      v = inN[ci * 16384 + iy * 128 + ix];
    s_in[e] = v;
  }
  __syncthreads();
  const float* wc = wT + cob;
#pragma unroll
  for (int c = 0; c < 3; ++c) {
    const float* base = s_in + c * 360 + py * 40 + px;
#pragma unroll
    for (int ky = 0; ky < 4; ++ky) {
#pragma unroll
      for (int kx = 0; kx < 4; ++kx) {
        float iv = base[ky * 20 + (kx & 1) * 10 + (kx >> 1)];
        const float* w = wc + (size_t)(c * 16 + ky * 4 + kx) * 256;  // uniform
#pragma unroll
        for (int i = 0; i < 16; ++i) acc[i] = fmaf(iv, w[i], acc[i]);
      }
    }
  }
  const int pxg = n * 4096 + (Y + py) * 64 + (X + px);
  uint p0[8], p1[8];
#pragma unroll
  for (int i = 0; i < 8; ++i) {
    float va = fmaxf(acc[2 * i], 0.f), vb = fmaxf(acc[2 * i + 1], 0.f);
    ushort_t a0 = f2bf(va), b0 = f2bf(vb);
    ushort_t a1 = f2bf(va - bf2f(a0)), b1 = f2bf(vb - bf2f(b0));
    p0[i] = (uint)a0 | ((uint)b0 << 16);
    p1[i] = (uint)a1 | ((uint)b1 << 16);
  }
  ushort_t* d0 = o0 + (size_t)pxg * 256 + cob;
  ushort_t* d1 = o1 + (size_t)pxg * 256 + cob;
  uint4 v0a; v0a.x = p0[0]; v0a.y = p0[1]; v0a.z = p0[2]; v0a.w = p0[3];
  uint4 v0b; v0b.x = p0[4]; v0b.y = p0[5]; v0b.z = p0[6]; v0b.w = p0[7];
  uint4 v1a; v1a.x = p1[0]; v1a.y = p1[1]; v1a.z = p1[2]; v1a.w = p1[3];
  uint4 v1b; v1b.x = p1[4]; v1b.y = p1[5]; v1b.z = p1[6]; v1b.w = p1[7];
  *(uint4*)d0 = v0a; *(uint4*)(d0 + 8) = v0b;
  *(uint4*)d1 = v1a; *(uint4*)(d1 + 8) = v1b;
}

// ---------- encoder implicit-GEMM MFMA, split-bf16, fused epilogue ----------
// D[co][px] = sum_{tap,ci} W[...] * X[...].  Block: 64co x 128px, 4 waves;
// wave: 64co x 32px = 4 m-tiles x 2 n-tiles of 16x16x32.  chunk = 32 k.
// 3 passes: w1x1 + w1x2 + w2x1.
template<int KIND, bool ADD, bool RELUV, bool WH, bool WS>
__global__ __launch_bounds__(256) void k_enc_mfma(
    const ushort_t* __restrict__ x0, const ushort_t* __restrict__ x1,
    const ushort_t* __restrict__ wp, const float* __restrict__ bias,
    float* __restrict__ h32, ushort_t* __restrict__ sp0, ushort_t* __restrict__ sp1)
{
  __shared__ ushort_t smem[18432];   // sA 4096 | sB 8192 ; epilogue: 2x128x72
  ushort_t* sA = smem;               // [pl][row64][k32]
  ushort_t* sB = smem + 4096;        // [pl][row128][k32]
  const int tid = threadIdx.x, lane = tid & 63, wv = tid >> 6;
  const int l15 = lane & 15, q = lane >> 4;
  const int pxT = blockIdx.x, coT = blockIdx.y;
  constexpr int NCH = (KIND == 0) ? 128 : (KIND == 1 ? 72 : 8);
  f32x4 acc[4][2];
#pragma unroll
  for (int m = 0; m < 4; ++m)
#pragma unroll
    for (int n = 0; n < 2; ++n) acc[m][n] = (f32x4){0.f, 0.f, 0.f, 0.f};

  // per-thread B-row geometry (row = tid>>1, k-half = tid&1)
  const int brow = tid >> 1, bhalf = tid & 1;
  const int bpx = pxT * 128 + brow;
  const int bimg = bpx >> 10, bp = bpx & 1023, bu = bp >> 5, bvc = bp & 31;
  int ptap = -1; size_t rowb = 0; bool bval = (KIND == 2);
  if (KIND == 2) rowb = ((size_t)bpx) << 8;

  for (int chunk = 0; chunk < NCH; ++chunk) {
    const int tap = chunk >> 3, cg = chunk & 7;
    if (KIND != 2 && tap != ptap) {
      ptap = tap;
      int ky, kx, iy, ix;
      if (KIND == 0) {
        ky = tap >> 2; kx = tap & 3;
        iy = 2 * bu - 1 + ky; ix = 2 * bvc - 1 + kx;
        bval = ((unsigned)iy < 64u) && ((unsigned)ix < 64u);
        rowb = ((size_t)(bimg * 4096 + iy * 64 + ix)) << 8;
      } else {
        ky = tap / 3; kx = tap - ky * 3;
        iy = bu - 1 + ky; ix = bvc - 1 + kx;
        bval = ((unsigned)iy < 32u) && ((unsigned)ix < 32u);
        rowb = ((size_t)(bimg * 1024 + iy * 32 + ix)) << 8;
      }
    }
    // global loads (before barrier, overlap with previous MFMA tail)
    uint4 bg[2][2];
    const int koff = cg * 32 + bhalf * 16;
    if (bval) {
      bg[0][0] = *(const uint4*)(x0 + rowb + koff);
      bg[0][1] = *(const uint4*)(x0 + rowb + koff + 8);
      bg[1][0] = *(const uint4*)(x1 + rowb + koff);
      bg[1][1] = *(const uint4*)(x1 + rowb + koff + 8);
    } else {
      uint4 z; z.x = 0; z.y = 0; z.z = 0; z.w = 0;
      bg[0][0] = z; bg[0][1] = z; bg[1][0] = z; bg[1][1] = z;
    }
    const ushort_t* ap = wp + ((size_t)(chunk * 4 + coT) << 12);
    uint4 av0 = *(const uint4*)(ap + tid * 8);
    uint4 av1 = *(const uint4*)(ap + (tid + 256) * 8);
    __syncthreads();
    *(uint4*)(sA + tid * 8) = av0;
    *(uint4*)(sA + (tid + 256) * 8) = av1;
    ushort_t* bd = sB + brow * 32 + bhalf * 16;
    *(uint4*)(bd) = bg[0][0];
    *(uint4*)(bd + 8) = bg[0][1];
    *(uint4*)(bd + 4096) = bg[1][0];
    *(uint4*)(bd + 4096 + 8) = bg[1][1];
    __syncthreads();
    short8 af[4][2], bf[2][2];
#pragma unroll
    for (int m = 0; m < 4; ++m)
#pragma unroll
      for (int pl = 0; pl < 2; ++pl)
        af[m][pl] = *(const short8*)(sA + pl * 2048 + (m * 16 + l15) * 32 + q * 8);
#pragma unroll
    for (int n = 0; n < 2; ++n)
#pragma unroll
      for (int pl = 0; pl < 2; ++pl)
        bf[n][pl] = *(const short8*)(sB + pl * 4096 + (wv * 32 + n * 16 + l15) * 32 + q * 8);
#pragma unroll
    for (int m = 0; m < 4; ++m)
#pragma unroll
      for (int n = 0; n < 2; ++n) {
        acc[m][n] = __builtin_amdgcn_mfma_f32_16x16x32_bf16(af[m][0], bf[n][0], acc[m][n], 0, 0, 0);
        acc[m][n] = __builtin_amdgcn_mfma_f32_16x16x32_bf16(af[m][0], bf[n][1], acc[m][n], 0, 0, 0);
        acc[m][n] = __builtin_amdgcn_mfma_f32_16x16x32_bf16(af[m][1], bf[n][0], acc[m][n], 0, 0, 0);
      }
  }
  __syncthreads();
  // fused epilogue: bias (+h_old) (+relu) -> h32; split(relu(val)) -> smem
#pragma unroll
  for (int m = 0; m < 4; ++m) {
#pragma unroll
    for (int n = 0; n < 2; ++n) {
#pragma unroll
      for (int r = 0; r < 4; ++r) {
        const int co_l = m * 16 + q * 4 + r;        // [0,64)
        const int px_l = wv * 32 + n * 16 + l15;    // [0,128)
        float v = acc[m][n][r] + bias[coT * 64 + co_l];
        const int px = pxT * 128 + px_l;
        const int img = px >> 10, pp = px & 1023;
        const size_t ha = ((size_t)(img * 256 + coT * 64 + co_l)) * 1024 + pp;
        if (ADD) v += h32[ha];
        if (RELUV) v = fmaxf(v, 0.f);
        if (WH) h32[ha] = v;
        if (WS) {
          float sv = fmaxf(v, 0.f);
          ushort_t b0 = f2bf(sv);
          smem[px_l * 72 + co_l] = b0;
          smem[9216 + px_l * 72 + co_l] = f2bf(sv - bf2f(b0));
        }
      }
    }
  }
  if (WS) {
    __syncthreads();
#pragma unroll
    for (int i = 0; i < 8; ++i) {
      int idx = tid + 256 * i;
      int pl = idx >> 10, w2 = idx & 1023, pxl = w2 >> 3, g = w2 & 7;
      uint4 vv = *(const uint4*)(smem + pl * 9216 + pxl * 72 + g * 8);
      ushort_t* dst = (pl ? sp1 : sp0) + ((size_t)(pxT * 128 + pxl)) * 256 + coT * 64 + g * 8;
      *(uint4*)dst = vv;
    }
  }
}

// ---------- 1x1 conv fp32 (to_z only) ----------
__global__ __launch_bounds__(256) void k_conv1x1(
    const float* __restrict__ in, float* __restrict__ out,
    const float* __restrict__ wT, const float* __restrict__ bias,
    int CI, int CO, int P)
{
  const int p = blockIdx.x * 256 + threadIdx.x;
  const int cob = blockIdx.y * 16;
  const int n = blockIdx.z;
  const float* inN = in + (size_t)n * CI * P + p;
  float acc[16];
#pragma unroll
  for (int i = 0; i < 16; ++i) acc[i] = bias[cob + i];
  const float* wr = wT + cob;
#pragma unroll 4
  for (int ci = 0; ci < CI; ++ci) {
    float iv = inN[(size_t)ci * P];
    const float* w = wr + (size_t)ci * CO;  // uniform
#pragma unroll
    for (int i = 0; i < 16; ++i) acc[i] = fmaf(iv, w[i], acc[i]);
  }
  float* outN = out + (size_t)n * CO * P + p;
#pragma unroll
  for (int i = 0; i < 16; ++i) outN[(size_t)(cob + i) * P] = acc[i];
}

// ---------- fused VQ: dots + argmin + ids + e_k gather ----------
__global__ __launch_bounds__(256) void k_vq(
    const float* __restrict__ z_e, const float* __restrict__ cb,
    const float* __restrict__ cnorm, float* __restrict__ ids_f,
    float* __restrict__ ek)
{
  int g = blockIdx.x * 256 + threadIdx.x;  // 8192 points
  int img = g >> 10, p = g & 1023;
  const float* zp = z_e + (size_t)img * 64 * 1024 + p;
  float z[64];
#pragma unroll
  for (int c = 0; c < 64; ++c) z[c] = zp[(size_t)c * 1024];
  float best = 3.4e38f; int bid = 0;
  for (int j = 0; j < 512; ++j) {
    const float* cj = cb + j * 64;  // uniform -> scalar loads
    float m = 0.f;
#pragma unroll
    for (int c = 0; c < 64; ++c) m = fmaf(z[c], cj[c], m);
    float d = fmaf(-2.f, m, cnorm[j]);
    if (d < best) { best = d; bid = j; }  // strict <: first-min (np.argmin)
  }
  ids_f[g] = (float)bid;
  const float* cbid = cb + bid * 64;
  float* ekp = ek + (size_t)img * 64 * 1024 + p;
#pragma unroll
  for (int c = 0; c < 64; ++c) ekp[(size_t)c * 1024] = cbid[c];
}

// ---------- from_z 1x1 (64->256) + relu -> NHWC bf16 ----------
__global__ __launch_bounds__(256) void k_from_z(
    const float* __restrict__ ek, ushort_t* __restrict__ nhwc,
    const float* __restrict__ wT, const float* __restrict__ bias)
{
  const int p = blockIdx.x * 256 + threadIdx.x;  // 0..1023
  const int co0 = blockIdx.y * 16;
  const int n = blockIdx.z;
  const float* inN = ek + (size_t)n * 64 * 1024 + p;
  float acc[16];
#pragma unroll
  for (int i = 0; i < 16; ++i) acc[i] = bias[co0 + i];
#pragma unroll 4
  for (int ci = 0; ci < 64; ++ci) {
    float iv = inN[(size_t)ci * 1024];
    const float* w = wT + (size_t)ci * 256 + co0;  // uniform
#pragma unroll
    for (int i = 0; i < 16; ++i) acc[i] = fmaf(iv, w[i], acc[i]);
  }
  uint pk[8];
#pragma unroll
  for (int i = 0; i < 8; ++i) {
    ushort_t lo = f2bf(fmaxf(acc[2 * i], 0.f));
    ushort_t hi = f2bf(fmaxf(acc[2 * i + 1], 0.f));
    pk[i] = (uint)lo | ((uint)hi << 16);
  }
  ushort_t* op = nhwc + (((size_t)n * 1024 + p) * 256 + co0);
  uint4 v0; v0.x = pk[0]; v0.y = pk[1]; v0.z = pk[2]; v0.w = pk[3];
  uint4 v1; v1.x = pk[4]; v1.y = pk[5]; v1.z = pk[6]; v1.w = pk[7];
  *(uint4*)(op) = v0;
  *(uint4*)(op + 8) = v1;
}

// ---------- t1 convtranspose 4x4 s2 p1, 256->256, bf16 MFMA, relu -> bf16 NHWC
__global__ __launch_bounds__(256) void k_mfma_t1(
    const ushort_t* __restrict__ nhwc, const ushort_t* __restrict__ wb,
    const float* __restrict__ bias, ushort_t* __restrict__ t1o)
{
  __shared__ ushort_t sA[128 * 32];
  __shared__ ushort_t sB[128 * 32];
  const int tid = threadIdx.x;
  const int lane = tid & 63;
  const int wv = tid >> 6;
  const int wm = wv & 1, wn = wv >> 1;
  const int l15 = lane & 15, q = lane >> 4;
  const int pxT = blockIdx.x, coT = blockIdx.y, par = blockIdx.z;
  const int ry = par & 1, rx = (par >> 1) & 1;
  const int pxbase = pxT * 128;
  const int img = pxbase >> 10;
  f32x4 acc[4][4];
#pragma unroll
  for (int i = 0; i < 4; ++i)
#pragma unroll
    for (int j = 0; j < 4; ++j) acc[i][j] = (f32x4){0.f, 0.f, 0.f, 0.f};

  for (int c = 0; c < 32; ++c) {
    const int tap = c >> 3, c8 = c & 7;
    const int a = tap >> 1, b = tap & 1;
    const ushort_t* Abase = wb + ((size_t)((par * 4 + tap) * 8 + c8) << 13);
#pragma unroll
    for (int r = 0; r < 2; ++r) {
      int idx = tid + 256 * r;
      int row = idx >> 2, kg = idx & 3;
      uint4 v = *(const uint4*)(Abase + ((coT * 128 + row) * 32 + kg * 8));
      *(uint4*)(&sA[row * 32 + kg * 8]) = v;
    }
#pragma unroll
    for (int r = 0; r < 2; ++r) {
      int idx = tid + 256 * r;
      int row = idx >> 2, kg = idx & 3;
      int px = pxbase + row;
      int u = (px >> 5) & 31, vv = px & 31;
      int iy = u + ry - a, ix = vv + rx - b;
      uint4 val;
      if ((unsigned)iy < 32u && (unsigned)ix < 32u) {
        val = *(const uint4*)(nhwc + ((size_t)(img * 1024 + iy * 32 + ix) * 256 + c8 * 32 + kg * 8));
      } else { val.x = 0u; val.y = 0u; val.z = 0u; val.w = 0u; }
      *(uint4*)(&sB[row * 32 + kg * 8]) = val;
    }
    __syncthreads();
    short8 af[4], bfr[4];
#pragma unroll
    for (int i = 0; i < 4; ++i)
      af[i] = *(const short8*)((const short*)sA + ((wm * 64 + i * 16 + l15) * 32 + q * 8));
#pragma unroll
    for (int j = 0; j < 4; ++j)
      bfr[j] = *(const short8*)((const short*)sB + ((wn * 64 + j * 16 + l15) * 32 + q * 8));
#pragma unroll
    for (int i = 0; i < 4; ++i)
#pragma unroll
      for (int j = 0; j < 4; ++j)
        acc[i][j] = __builtin_amdgcn_mfma_f32_16x16x32_bf16(af[i], bfr[j], acc[i][j], 0, 0, 0);
    __syncthreads();
  }
  // epilogue: relu + bf16 NHWC store
#pragma unroll
  for (int i = 0; i < 4; ++i) {
    int co = coT * 128 + wm * 64 + i * 16 + q * 4;
#pragma unroll
    for (int j = 0; j < 4; ++j) {
      int px = pxbase + wn * 64 + j * 16 + l15;
      int u = (px >> 5) & 31, vv = px & 31;
      int oy = 2 * u + ry, ox = 2 * vv + rx;
      ushort_t e0 = f2bf(fmaxf(acc[i][j][0] + bias[co + 0], 0.f));
      ushort_t e1 = f2bf(fmaxf(acc[i][j][1] + bias[co + 1], 0.f));
      ushort_t e2 = f2bf(fmaxf(acc[i][j][2] + bias[co + 2], 0.f));
      ushort_t e3 = f2bf(fmaxf(acc[i][j][3] + bias[co + 3], 0.f));
      uint2 pk; pk.x = (uint)e0 | ((uint)e1 << 16); pk.y = (uint)e2 | ((uint)e3 << 16);
      *(uint2*)(t1o + ((size_t)(img * 4096 + oy * 64 + ox) * 256 + co)) = pk;
    }
  }
}

// ---------- t2 convtranspose 4x4 s2 p1, 256->3, bf16 MFMA, sigmoid ----------
// px-as-M: per parity, D[px][co] = sum_k In[px][k] W[k][co]; N=16 (3 used).
__global__ __launch_bounds__(256) void k_mfma_t2(
    const ushort_t* __restrict__ t1o, const ushort_t* __restrict__ wb,
    const float* __restrict__ bias, float* __restrict__ out)
{
  __shared__ ushort_t sA2[256 * 32];  // [pxrow][k32]
  __shared__ ushort_t sB2[16 * 32];   // [co][k32]
  const int tid = threadIdx.x, lane = tid & 63, wv = tid >> 6;
  const int l15 = lane & 15, q = lane >> 4;
  const int pxb = blockIdx.x * 256;
  const int par = blockIdx.y;
  const int ry = par & 1, rx = (par >> 1) & 1;
  f32x4 acc[4];
#pragma unroll
  for (int m = 0; m < 4; ++m) acc[m] = (f32x4){0.f, 0.f, 0.f, 0.f};
  const int kg = tid & 3;
  size_t rb[4]; bool rv[4];
  for (int chunk = 0; chunk < 32; ++chunk) {
    const int tap = chunk >> 3, cg = chunk & 7;
    const int a = tap >> 1, b = tap & 1;
    if ((chunk & 7) == 0) {
#pragma unroll
      for (int i = 0; i < 4; ++i) {
        int row = (tid >> 2) + 64 * i;
        int px = pxb + row;
        int img = px >> 12, p = px & 4095, u = p >> 6, v = p & 63;
        int iy = u + ry - a, ix = v + rx - b;
        rv[i] = ((unsigned)iy < 64u) && ((unsigned)ix < 64u);
        rb[i] = ((size_t)(img * 4096 + iy * 64 + ix)) << 8;
      }
    }
    uint4 av[4];
#pragma unroll
    for (int i = 0; i < 4; ++i) {
      if (rv[i]) av[i] = *(const uint4*)(t1o + rb[i] + cg * 32 + kg * 8);
      else { av[i].x = 0; av[i].y = 0; av[i].z = 0; av[i].w = 0; }
    }
    uint4 bv;
    if (tid < 64) bv = *(const uint4*)(wb + ((size_t)(par * 32 + chunk)) * 512 + tid * 8);
    __syncthreads();
#pragma unroll
    for (int i = 0; i < 4; ++i)
      *(uint4*)(sA2 + ((tid >> 2) + 64 * i) * 32 + kg * 8) = av[i];
    if (tid < 64) *(uint4*)(sB2 + tid * 8) = bv;
    __syncthreads();
    short8 bf = *(const short8*)(sB2 + l15 * 32 + q * 8);
#pragma unroll
    for (int m = 0; m < 4; ++m) {
      short8 af = *(const short8*)(sA2 + (wv * 64 + m * 16 + l15) * 32 + q * 8);
      acc[m] = __builtin_amdgcn_mfma_f32_16x16x32_bf16(af, bf, acc[m], 0, 0, 0);
    }
    __syncthreads();
  }
  const int co = l15;
  if (co < 3) {
    float bco = bias[co];
#pragma unroll
    for (int m = 0; m < 4; ++m) {
#pragma unroll
      for (int r = 0; r < 4; ++r) {
        int px = pxb + wv * 64 + m * 16 + q * 4 + r;
        int img = px >> 12, p = px & 4095, u = p >> 6, v = p & 63;
        size_t addr = ((size_t)(img * 3 + co)) * 16384 + (2 * u + ry) * 128 + (2 * v + rx);
        out[addr] = 1.f / (1.f + expf(-(acc[m][r] + bco)));
      }
    }
  }
}

// ---------------------------------------------------------------------------
extern "C" void kernel_launch(void* const* d_in, const int* in_sizes, int n_in,
                              void* d_out, int out_size, void* d_ws, size_t ws_size,
                              hipStream_t stream) {
  (void)in_sizes; (void)n_in; (void)out_size; (void)ws_size;
  const float* x      = (const float*)d_in[0];
  const float* c1_w   = (const float*)d_in[1];
  const float* c1_b   = (const float*)d_in[2];
  const float* c2_w   = (const float*)d_in[3];
  const float* c2_b   = (const float*)d_in[4];
  const float* r0_w3  = (const float*)d_in[5];
  const float* r0_b3  = (const float*)d_in[6];
  const float* r0_w1  = (const float*)d_in[7];
  const float* r0_b1  = (const float*)d_in[8];
  const float* r1_w3  = (const float*)d_in[9];
  const float* r1_b3  = (const float*)d_in[10];
  const float* r1_w1  = (const float*)d_in[11];
  const float* r1_b1  = (const float*)d_in[12];
  const float* to_z_w = (const float*)d_in[13];
  const float* to_z_b = (const float*)d_in[14];
  const float* cb     = (const float*)d_in[15];
  const float* from_z_w = (const float*)d_in[16];
  const float* from_z_b = (const float*)d_in[17];
  const float* t1_w   = (const float*)d_in[18];
  const float* t1_b   = (const float*)d_in[19];
  const float* t2_w   = (const float*)d_in[20];
  const float* t2_b   = (const float*)d_in[21];

  float* wsf = (float*)d_ws;
  // region [0, 8388608): conv1 split planes; reused by decoder buffers + SplitB
  ushort_t* xs1p0 = (ushort_t*)(wsf + 0);        // 8,388,608 u16
  ushort_t* xs1p1 = (ushort_t*)(wsf + 4194304);  // 8,388,608 u16
  ushort_t* spB0  = (ushort_t*)(wsf + 0);        // 2,097,152 u16 (post-conv2 era)
  ushort_t* spB1  = (ushort_t*)(wsf + 1048576);
  ushort_t* t1out = (ushort_t*)(wsf + 2097152);  // 8,388,608 u16 (decoder era)
  ushort_t* decn  = (ushort_t*)(wsf + 6291456);  // 2,097,152 u16 (decoder era)
  float*    h32   = wsf + 8388608;               // 2,097,152 f
  ushort_t* spA0  = (ushort_t*)(wsf + 10485760);
  ushort_t* spA1  = (ushort_t*)(wsf + 11534336);
  ushort_t* wp_c2   = (ushort_t*)(wsf + 12582912);  // 2,097,152 u16
  ushort_t* wp_r0w3 = (ushort_t*)(wsf + 13631488);  // 1,179,648 u16
  ushort_t* wp_r1w3 = (ushort_t*)(wsf + 14221312);
  ushort_t* wp_r0w1 = (ushort_t*)(wsf + 14811136);  // 131,072 u16
  ushort_t* wp_r1w1 = (ushort_t*)(wsf + 14876672);
  float*    wt_c1   = wsf + 14942208;               // 12,288 f
  float*    wt_toz  = wsf + 14954496;               // 16,384 f
  float*    wt_fromz= wsf + 14970880;               // 16,384 f
  ushort_t* t1wb    = (ushort_t*)(wsf + 14987264);  // 1,048,576 u16
  ushort_t* w2pk    = (ushort_t*)(wsf + 15511552);  // 65,536 u16
  float*    cnorm   = wsf + 15544320;               // 512 f

  float* out_img = (float*)d_out;        // 393216
  float* z_e_out = out_img + 393216;     // 524288
  float* e_k_out = z_e_out + 524288;     // 524288
  float* ids_out = e_k_out + 524288;     // 8192 (stored as float)

  // ---- weight prep ----
  k_transpose_w<<<48, 256, 0, stream>>>(c1_w, wt_c1, 256, 48);
  k_transpose_w<<<64, 256, 0, stream>>>(to_z_w, wt_toz, 64, 256);
  k_transpose_w<<<64, 256, 0, stream>>>(from_z_w, wt_fromz, 256, 64);
  k_prep_enc<0><<<8192, 256, 0, stream>>>(c2_w,  wp_c2,   128 << 14);
  k_prep_enc<1><<<4608, 256, 0, stream>>>(r0_w3, wp_r0w3, 72 << 14);
  k_prep_enc<1><<<4608, 256, 0, stream>>>(r1_w3, wp_r1w3, 72 << 14);
  k_prep_enc<2><<<512,  256, 0, stream>>>(r0_w1, wp_r0w1, 8 << 14);
  k_prep_enc<2><<<512,  256, 0, stream>>>(r1_w1, wp_r1w1, 8 << 14);
  k_prep_t1w<<<4096, 256, 0, stream>>>(t1_w, t1wb);
  k_prep_t2w<<<256, 256, 0, stream>>>(t2_w, w2pk);
  k_prep_cb<<<2, 256, 0, stream>>>(cb, cnorm);

  // ---- encoder ----
  k_conv1_split<<<dim3(64, 4, 8), 256, 0, stream>>>(x, xs1p0, xs1p1, wt_c1, c1_b);
  // conv2: h = relu(.); write h32 + split
  k_enc_mfma<0, false, true,  true,  true ><<<dim3(64, 4), 256, 0, stream>>>(
      xs1p0, xs1p1, wp_c2, c2_b, h32, spA0, spA1);
  // r0 w3: r = conv(.); split(relu(r))
  k_enc_mfma<1, false, false, false, true ><<<dim3(64, 4), 256, 0, stream>>>(
      spA0, spA1, wp_r0w3, r0_b3, nullptr, spB0, spB1);
  // r0 w1: h += r2; write h32 + split(relu(h))
  k_enc_mfma<2, true,  false, true,  true ><<<dim3(64, 4), 256, 0, stream>>>(
      spB0, spB1, wp_r0w1, r0_b1, h32, spA0, spA1);
  // r1 w3
  k_enc_mfma<1, false, false, false, true ><<<dim3(64, 4), 256, 0, stream>>>(
      spA0, spA1, wp_r1w3, r1_b3, nullptr, spB0, spB1);
  // r1 w1: h += r2; write h32 only
  k_enc_mfma<2, true,  false, true,  false><<<dim3(64, 4), 256, 0, stream>>>(
      spB0, spB1, wp_r1w1, r1_b1, h32, nullptr, nullptr);
  // to_z (fp32)
  k_conv1x1<<<dim3(4, 4, 8), 256, 0, stream>>>(h32, z_e_out, wt_toz, to_z_b, 256, 64, 1024);

  // ---- VQ ----
  k_vq<<<32, 256, 0, stream>>>(z_e_out, cb, cnorm, ids_out, e_k_out);

  // ---- decoder (bf16) ----
  k_from_z<<<dim3(4, 16, 8), 256, 0, stream>>>(e_k_out, decn, wt_fromz, from_z_b);
  k_mfma_t1<<<dim3(64, 2, 4), 256, 0, stream>>>(decn, t1wb, t1_b, t1out);
  k_mfma_t2<<<dim3(128, 4), 256, 0, stream>>>(t1out, w2pk, t2_b, out_img);
}

// Round 4
// 530.275 us; speedup vs baseline: 3.3891x; 1.4285x over previous
//
#include <hip/hip_runtime.h>
#include <math.h>

// ---------------------------------------------------------------------------
// VQ-VAE forward.
// Encoder: 256-ch convs as implicit-GEMM MFMA with 2-term bf16 split inputs
// (3 passes: w1x1 + w1x2 + w2x1). Big convs split-K=2 (atomicAdd fp32 partial,
// deterministic: exactly 2 commutative adds) + fused-epilogue kernel.
// VQ: chunk-parallel (16x) partial argmin + reduce; bit-identical to serial.
// Decoder: t1 + t2 plain bf16 MFMA.
// ---------------------------------------------------------------------------

typedef unsigned int uint;
typedef unsigned short ushort_t;
using short8 = __attribute__((ext_vector_type(8))) short;
using f32x4  = __attribute__((ext_vector_type(4))) float;

static __device__ __forceinline__ int rfl(int x) { return __builtin_amdgcn_readfirstlane(x); }
static __device__ __forceinline__ ushort_t f2bf(float f) {
  uint u = __float_as_uint(f);
  return (ushort_t)((u + 0x7fffu + ((u >> 16) & 1u)) >> 16);  // RNE; finite inputs
}
static __device__ __forceinline__ float bf2f(ushort_t b) {
  return __uint_as_float(((uint)b) << 16);
}

// ---------- weight prep ----------
__global__ void k_transpose_w(const float* __restrict__ w, float* __restrict__ wT, int CO, int CIKK) {
  int idx = blockIdx.x * 256 + threadIdx.x;
  if (idx >= CO * CIKK) return;
  int co = idx % CO, i = idx / CO;
  wT[idx] = w[co * CIKK + i];
}

// encoder MFMA weight pack: w[co][ci(256)][KH][KW] fp32 ->
// wp[chunk][coT(4)][pl(2)][row(64)][k(32)] bf16 split, chunk = tap*8 + cg
template<int KIND>  // 0: 4x4 (16 taps), 1: 3x3 (9 taps), 2: 1x1 (1 tap)
__global__ void k_prep_enc(const float* __restrict__ w, ushort_t* __restrict__ wp, int total) {
  int idx = blockIdx.x * 256 + threadIdx.x;
  if (idx >= total) return;
  int k = idx & 31, row = (idx >> 5) & 63, pl = (idx >> 11) & 1, coT = (idx >> 12) & 3, chunk = idx >> 14;
  int tap = chunk >> 3, cg = chunk & 7;
  int co = coT * 64 + row, ci = cg * 32 + k;
  int ky, kx, KK, KW;
  if (KIND == 0)      { ky = tap >> 2; kx = tap & 3;       KK = 16; KW = 4; }
  else if (KIND == 1) { ky = tap / 3;  kx = tap - ky * 3;  KK = 9;  KW = 3; }
  else                { ky = 0;        kx = 0;             KK = 1;  KW = 1; }
  float v = w[(co * 256 + ci) * KK + ky * KW + kx];
  ushort_t b0 = f2bf(v);
  wp[idx] = pl ? f2bf(v - bf2f(b0)) : b0;
}

// t1_w [ci][co][ky][kx] -> bf16 [par][tap][c8][co][kk32]
__global__ void k_prep_t1w(const float* __restrict__ w, ushort_t* __restrict__ wb) {
  int idx = blockIdx.x * 256 + threadIdx.x;  // 1048576
  int kk  = idx & 31;
  int co  = (idx >> 5) & 255;
  int c8  = (idx >> 13) & 7;
  int tap = (idx >> 16) & 3;
  int par = idx >> 18;
  int ry = par & 1, rx = (par >> 1) & 1;
  int a = tap >> 1, b = tap & 1;
  int ky = ((ry + 1) & 1) + 2 * a;
  int kx = ((rx + 1) & 1) + 2 * b;
  int ci = c8 * 32 + kk;
  wb[idx] = f2bf(w[((ci * 256 + co) << 4) + ky * 4 + kx]);
}

// t2_w [ci(256)][co(3)][4][4] -> bf16 [par(4)][chunk(32)][co16][k32]
__global__ void k_prep_t2w(const float* __restrict__ w, ushort_t* __restrict__ wb) {
  int idx = blockIdx.x * 256 + threadIdx.x;  // 65536
  int k = idx & 31, co = (idx >> 5) & 15, chunk = (idx >> 9) & 31, par = idx >> 14;
  int tap = chunk >> 3, cg = chunk & 7;
  int a = tap >> 1, b = tap & 1;
  int ry = par & 1, rx = (par >> 1) & 1;
  int ky = ((ry + 1) & 1) + 2 * a;
  int kx = ((rx + 1) & 1) + 2 * b;
  int ci = cg * 32 + k;
  float v = (co < 3) ? w[((ci * 3 + co) << 4) + ky * 4 + kx] : 0.f;
  wb[idx] = f2bf(v);
}

// cnorm[j] = sum_c cb[j][c]^2
__global__ void k_prep_cb(const float* __restrict__ cb, float* __restrict__ cnorm) {
  int idx = blockIdx.x * 256 + threadIdx.x;
  if (idx < 512) {
    float s = 0.f;
    for (int c = 0; c < 64; ++c) { float v = cb[idx * 64 + c]; s = fmaf(v, v, s); }
    cnorm[idx] = s;
  }
}

// ---------- conv1: 3->256, 4x4 s2 p1, relu, output split-bf16 NHWC ----------
__global__ __launch_bounds__(256) void k_conv1_split(
    const float* __restrict__ in, ushort_t* __restrict__ o0, ushort_t* __restrict__ o1,
    const float* __restrict__ wT, const float* __restrict__ bias)
{
  __shared__ float s_in[3 * 360];  // parity-split cols, pitch 20 (2-way free)
  const int tid = threadIdx.x;
  const int lane = tid & 63;
  const int wv = rfl(tid >> 6);
  const int px = lane & 7, py = lane >> 3;
  const int tx = blockIdx.x & 7, ty = blockIdx.x >> 3;
  const int X = tx * 8, Y = ty * 8;
  const int cob = blockIdx.y * 64 + wv * 16;
  const int n = blockIdx.z;
  float acc[16];
#pragma unroll
  for (int i = 0; i < 16; ++i) acc[i] = bias[cob + i];
  const float* inN = in + (size_t)n * 3 * 16384;
  for (int e = tid; e < 3 * 360; e += 256) {
    int col2 = e % 20; int t = e / 20; int row = t % 18; int ci = t / 18;
    int pr = col2 / 10, hc = col2 % 10, ixl = 2 * hc + pr;
    int iy = 2 * Y - 1 + row, ix = 2 * X - 1 + ixl;
    float v = 0.f;
    if (ixl < 18 && (unsigned)iy < 128u && (unsigned)ix < 128u)
      v = inN[ci * 16384 + iy * 128 + ix];
    s_in[e] = v;
  }
  __syncthreads();
  const float* wc = wT + cob;
#pragma unroll
  for (int c = 0; c < 3; ++c) {
    const float* base = s_in + c * 360 + py * 40 + px;
#pragma unroll
    for (int ky = 0; ky < 4; ++ky) {
#pragma unroll
      for (int kx = 0; kx < 4; ++kx) {
        float iv = base[ky * 20 + (kx & 1) * 10 + (kx >> 1)];
        const float* w = wc + (size_t)(c * 16 + ky * 4 + kx) * 256;  // uniform
#pragma unroll
        for (int i = 0; i < 16; ++i) acc[i] = fmaf(iv, w[i], acc[i]);
      }
    }
  }
  const int pxg = n * 4096 + (Y + py) * 64 + (X + px);
  uint p0[8], p1[8];
#pragma unroll
  for (int i = 0; i < 8; ++i) {
    float va = fmaxf(acc[2 * i], 0.f), vb = fmaxf(acc[2 * i + 1], 0.f);
    ushort_t a0 = f2bf(va), b0 = f2bf(vb);
    ushort_t a1 = f2bf(va - bf2f(a0)), b1 = f2bf(vb - bf2f(b0));
    p0[i] = (uint)a0 | ((uint)b0 << 16);
    p1[i] = (uint)a1 | ((uint)b1 << 16);
  }
  ushort_t* d0 = o0 + (size_t)pxg * 256 + cob;
  ushort_t* d1 = o1 + (size_t)pxg * 256 + cob;
  uint4 v0a; v0a.x = p0[0]; v0a.y = p0[1]; v0a.z = p0[2]; v0a.w = p0[3];
  uint4 v0b; v0b.x = p0[4]; v0b.y = p0[5]; v0b.z = p0[6]; v0b.w = p0[7];
  uint4 v1a; v1a.x = p1[0]; v1a.y = p1[1]; v1a.z = p1[2]; v1a.w = p1[3];
  uint4 v1b; v1b.x = p1[4]; v1b.y = p1[5]; v1b.z = p1[6]; v1b.w = p1[7];
  *(uint4*)d0 = v0a; *(uint4*)(d0 + 8) = v0b;
  *(uint4*)d1 = v1a; *(uint4*)(d1 + 8) = v1b;
}

// ---------- encoder implicit-GEMM MFMA, split-K=2, atomicAdd partial ----------
// Block: 64co x 128px, 4 waves; wave: 64co x 32px = 4x2 of 16x16x32; 3 passes.
// grid (pxT 64, coT 4, kz 2); partial in h32 layout, pre-zeroed.
template<int KIND>  // 0: conv2 (128 chunks), 1: 3x3 (72 chunks)
__global__ __launch_bounds__(256) void k_enc_mfma_split(
    const ushort_t* __restrict__ x0, const ushort_t* __restrict__ x1,
    const ushort_t* __restrict__ wp, float* __restrict__ part)
{
  __shared__ ushort_t smem[12288];   // sA 4096 | sB 8192 (ushorts)
  ushort_t* sA = smem;               // [pl][row64][k32]
  ushort_t* sB = smem + 4096;        // [pl][row128][k32]
  const int tid = threadIdx.x, lane = tid & 63, wv = tid >> 6;
  const int l15 = lane & 15, q = lane >> 4;
  const int pxT = blockIdx.x, coT = blockIdx.y;
  constexpr int NCH = (KIND == 0) ? 128 : 72;
  const int CH0 = blockIdx.z * (NCH / 2), CH1 = CH0 + NCH / 2;
  f32x4 acc[4][2];
#pragma unroll
  for (int m = 0; m < 4; ++m)
#pragma unroll
    for (int n = 0; n < 2; ++n) acc[m][n] = (f32x4){0.f, 0.f, 0.f, 0.f};

  const int brow = tid >> 1, bhalf = tid & 1;
  const int bpx = pxT * 128 + brow;
  const int bimg = bpx >> 10, bp = bpx & 1023, bu = bp >> 5, bvc = bp & 31;
  int ptap = -1; size_t rowb = 0; bool bval = false;

  for (int chunk = CH0; chunk < CH1; ++chunk) {
    const int tap = chunk >> 3, cg = chunk & 7;
    if (tap != ptap) {
      ptap = tap;
      int ky, kx, iy, ix;
      if (KIND == 0) {
        ky = tap >> 2; kx = tap & 3;
        iy = 2 * bu - 1 + ky; ix = 2 * bvc - 1 + kx;
        bval = ((unsigned)iy < 64u) && ((unsigned)ix < 64u);
        rowb = ((size_t)(bimg * 4096 + iy * 64 + ix)) << 8;
      } else {
        ky = tap / 3; kx = tap - ky * 3;
        iy = bu - 1 + ky; ix = bvc - 1 + kx;
        bval = ((unsigned)iy < 32u) && ((unsigned)ix < 32u);
        rowb = ((size_t)(bimg * 1024 + iy * 32 + ix)) << 8;
      }
    }
    uint4 bg[2][2];
    const int koff = cg * 32 + bhalf * 16;
    if (bval) {
      bg[0][0] = *(const uint4*)(x0 + rowb + koff);
      bg[0][1] = *(const uint4*)(x0 + rowb + koff + 8);
      bg[1][0] = *(const uint4*)(x1 + rowb + koff);
      bg[1][1] = *(const uint4*)(x1 + rowb + koff + 8);
    } else {
      uint4 z; z.x = 0; z.y = 0; z.z = 0; z.w = 0;
      bg[0][0] = z; bg[0][1] = z; bg[1][0] = z; bg[1][1] = z;
    }
    const ushort_t* ap = wp + ((size_t)(chunk * 4 + coT) << 12);
    uint4 av0 = *(const uint4*)(ap + tid * 8);
    uint4 av1 = *(const uint4*)(ap + (tid + 256) * 8);
    __syncthreads();
    *(uint4*)(sA + tid * 8) = av0;
    *(uint4*)(sA + (tid + 256) * 8) = av1;
    ushort_t* bd = sB + brow * 32 + bhalf * 16;
    *(uint4*)(bd) = bg[0][0];
    *(uint4*)(bd + 8) = bg[0][1];
    *(uint4*)(bd + 4096) = bg[1][0];
    *(uint4*)(bd + 4096 + 8) = bg[1][1];
    __syncthreads();
    short8 af[4][2], bf[2][2];
#pragma unroll
    for (int m = 0; m < 4; ++m)
#pragma unroll
      for (int pl = 0; pl < 2; ++pl)
        af[m][pl] = *(const short8*)(sA + pl * 2048 + (m * 16 + l15) * 32 + q * 8);
#pragma unroll
    for (int n = 0; n < 2; ++n)
#pragma unroll
      for (int pl = 0; pl < 2; ++pl)
        bf[n][pl] = *(const short8*)(sB + pl * 4096 + (wv * 32 + n * 16 + l15) * 32 + q * 8);
#pragma unroll
    for (int m = 0; m < 4; ++m)
#pragma unroll
      for (int n = 0; n < 2; ++n) {
        acc[m][n] = __builtin_amdgcn_mfma_f32_16x16x32_bf16(af[m][0], bf[n][0], acc[m][n], 0, 0, 0);
        acc[m][n] = __builtin_amdgcn_mfma_f32_16x16x32_bf16(af[m][0], bf[n][1], acc[m][n], 0, 0, 0);
        acc[m][n] = __builtin_amdgcn_mfma_f32_16x16x32_bf16(af[m][1], bf[n][0], acc[m][n], 0, 0, 0);
      }
  }
  // accumulate: exactly 2 fp32 atomic adds/element (commutative -> deterministic)
#pragma unroll
  for (int m = 0; m < 4; ++m) {
#pragma unroll
    for (int n = 0; n < 2; ++n) {
#pragma unroll
      for (int r = 0; r < 4; ++r) {
        const int co_l = m * 16 + q * 4 + r;
        const int px_l = wv * 32 + n * 16 + l15;
        const int px = pxT * 128 + px_l;
        const int img = px >> 10, pp = px & 1023;
        const size_t ha = ((size_t)(img * 256 + coT * 64 + co_l)) * 1024 + pp;
        atomicAdd(&part[ha], acc[m][n][r]);
      }
    }
  }
}

// ---------- epilogue for split convs ----------
// WH (conv2): v=relu(part+bias); h32=v; split v.   !WH (3x3): split relu(part+bias).
template<bool WH>
__global__ __launch_bounds__(256) void k_enc_epi(
    const float* __restrict__ part, float* __restrict__ h32,
    ushort_t* __restrict__ s0, ushort_t* __restrict__ s1,
    const float* __restrict__ bias)
{
  const int px = blockIdx.x * 256 + threadIdx.x;  // 8192
  const int co0 = blockIdx.y * 16;
  const int img = px >> 10, pp = px & 1023;
  uint p0[8], p1[8];
#pragma unroll
  for (int i = 0; i < 8; ++i) {
    size_t ha = ((size_t)(img * 256 + co0 + 2 * i)) * 1024 + pp;
    size_t hb = ha + 1024;
    float va = part[ha] + bias[co0 + 2 * i];
    float vb = part[hb] + bias[co0 + 2 * i + 1];
    float sa, sb;
    if (WH) {
      va = fmaxf(va, 0.f); vb = fmaxf(vb, 0.f);
      h32[ha] = va; h32[hb] = vb; sa = va; sb = vb;
    } else { sa = fmaxf(va, 0.f); sb = fmaxf(vb, 0.f); }
    ushort_t a0 = f2bf(sa), b0 = f2bf(sb);
    p0[i] = (uint)a0 | ((uint)b0 << 16);
    p1[i] = (uint)f2bf(sa - bf2f(a0)) | ((uint)f2bf(sb - bf2f(b0)) << 16);
  }
  ushort_t* d0 = s0 + (size_t)px * 256 + co0;
  ushort_t* d1 = s1 + (size_t)px * 256 + co0;
  uint4 v0a; v0a.x = p0[0]; v0a.y = p0[1]; v0a.z = p0[2]; v0a.w = p0[3];
  uint4 v0b; v0b.x = p0[4]; v0b.y = p0[5]; v0b.z = p0[6]; v0b.w = p0[7];
  uint4 v1a; v1a.x = p1[0]; v1a.y = p1[1]; v1a.z = p1[2]; v1a.w = p1[3];
  uint4 v1b; v1b.x = p1[4]; v1b.y = p1[5]; v1b.z = p1[6]; v1b.w = p1[7];
  *(uint4*)d0 = v0a; *(uint4*)(d0 + 8) = v0b;
  *(uint4*)d1 = v1a; *(uint4*)(d1 + 8) = v1b;
}

// ---------- encoder 1x1 MFMA (unsplit, fused epilogue; round-3 verified) ----------
template<int KIND, bool ADD, bool RELUV, bool WH, bool WS>
__global__ __launch_bounds__(256) void k_enc_mfma(
    const ushort_t* __restrict__ x0, const ushort_t* __restrict__ x1,
    const ushort_t* __restrict__ wp, const float* __restrict__ bias,
    float* __restrict__ h32, ushort_t* __restrict__ sp0, ushort_t* __restrict__ sp1)
{
  __shared__ ushort_t smem[18432];   // sA 4096 | sB 8192 ; epilogue: 2x128x72
  ushort_t* sA = smem;
  ushort_t* sB = smem + 4096;
  const int tid = threadIdx.x, lane = tid & 63, wv = tid >> 6;
  const int l15 = lane & 15, q = lane >> 4;
  const int pxT = blockIdx.x, coT = blockIdx.y;
  constexpr int NCH = (KIND == 0) ? 128 : (KIND == 1 ? 72 : 8);
  f32x4 acc[4][2];
#pragma unroll
  for (int m = 0; m < 4; ++m)
#pragma unroll
    for (int n = 0; n < 2; ++n) acc[m][n] = (f32x4){0.f, 0.f, 0.f, 0.f};

  const int brow = tid >> 1, bhalf = tid & 1;
  const int bpx = pxT * 128 + brow;
  const int bimg = bpx >> 10, bp = bpx & 1023, bu = bp >> 5, bvc = bp & 31;
  int ptap = -1; size_t rowb = 0; bool bval = (KIND == 2);
  if (KIND == 2) rowb = ((size_t)bpx) << 8;

  for (int chunk = 0; chunk < NCH; ++chunk) {
    const int tap = chunk >> 3, cg = chunk & 7;
    if (KIND != 2 && tap != ptap) {
      ptap = tap;
      int ky, kx, iy, ix;
      if (KIND == 0) {
        ky = tap >> 2; kx = tap & 3;
        iy = 2 * bu - 1 + ky; ix = 2 * bvc - 1 + kx;
        bval = ((unsigned)iy < 64u) && ((unsigned)ix < 64u);
        rowb = ((size_t)(bimg * 4096 + iy * 64 + ix)) << 8;
      } else {
        ky = tap / 3; kx = tap - ky * 3;
        iy = bu - 1 + ky; ix = bvc - 1 + kx;
        bval = ((unsigned)iy < 32u) && ((unsigned)ix < 32u);
        rowb = ((size_t)(bimg * 1024 + iy * 32 + ix)) << 8;
      }
    }
    uint4 bg[2][2];
    const int koff = cg * 32 + bhalf * 16;
    if (bval) {
      bg[0][0] = *(const uint4*)(x0 + rowb + koff);
      bg[0][1] = *(const uint4*)(x0 + rowb + koff + 8);
      bg[1][0] = *(const uint4*)(x1 + rowb + koff);
      bg[1][1] = *(const uint4*)(x1 + rowb + koff + 8);
    } else {
      uint4 z; z.x = 0; z.y = 0; z.z = 0; z.w = 0;
      bg[0][0] = z; bg[0][1] = z; bg[1][0] = z; bg[1][1] = z;
    }
    const ushort_t* ap = wp + ((size_t)(chunk * 4 + coT) << 12);
    uint4 av0 = *(const uint4*)(ap + tid * 8);
    uint4 av1 = *(const uint4*)(ap + (tid + 256) * 8);
    __syncthreads();
    *(uint4*)(sA + tid * 8) = av0;
    *(uint4*)(sA + (tid + 256) * 8) = av1;
    ushort_t* bd = sB + brow * 32 + bhalf * 16;
    *(uint4*)(bd) = bg[0][0];
    *(uint4*)(bd + 8) = bg[0][1];
    *(uint4*)(bd + 4096) = bg[1][0];
    *(uint4*)(bd + 4096 + 8) = bg[1][1];
    __syncthreads();
    short8 af[4][2], bf[2][2];
#pragma unroll
    for (int m = 0; m < 4; ++m)
#pragma unroll
      for (int pl = 0; pl < 2; ++pl)
        af[m][pl] = *(const short8*)(sA + pl * 2048 + (m * 16 + l15) * 32 + q * 8);
#pragma unroll
    for (int n = 0; n < 2; ++n)
#pragma unroll
      for (int pl = 0; pl < 2; ++pl)
        bf[n][pl] = *(const short8*)(sB + pl * 4096 + (wv * 32 + n * 16 + l15) * 32 + q * 8);
#pragma unroll
    for (int m = 0; m < 4; ++m)
#pragma unroll
      for (int n = 0; n < 2; ++n) {
        acc[m][n] = __builtin_amdgcn_mfma_f32_16x16x32_bf16(af[m][0], bf[n][0], acc[m][n], 0, 0, 0);
        acc[m][n] = __builtin_amdgcn_mfma_f32_16x16x32_bf16(af[m][0], bf[n][1], acc[m][n], 0, 0, 0);
        acc[m][n] = __builtin_amdgcn_mfma_f32_16x16x32_bf16(af[m][1], bf[n][0], acc[m][n], 0, 0, 0);
      }
  }
  __syncthreads();
#pragma unroll
  for (int m = 0; m < 4; ++m) {
#pragma unroll
    for (int n = 0; n < 2; ++n) {
#pragma unroll
      for (int r = 0; r < 4; ++r) {
        const int co_l = m * 16 + q * 4 + r;
        const int px_l = wv * 32 + n * 16 + l15;
        float v = acc[m][n][r] + bias[coT * 64 + co_l];
        const int px = pxT * 128 + px_l;
        const int img = px >> 10, pp = px & 1023;
        const size_t ha = ((size_t)(img * 256 + coT * 64 + co_l)) * 1024 + pp;
        if (ADD) v += h32[ha];
        if (RELUV) v = fmaxf(v, 0.f);
        if (WH) h32[ha] = v;
        if (WS) {
          float sv = fmaxf(v, 0.f);
          ushort_t b0 = f2bf(sv);
          smem[px_l * 72 + co_l] = b0;
          smem[9216 + px_l * 72 + co_l] = f2bf(sv - bf2f(b0));
        }
      }
    }
  }
  if (WS) {
    __syncthreads();
#pragma unroll
    for (int i = 0; i < 8; ++i) {
      int idx = tid + 256 * i;
      int pl = idx >> 10, w2 = idx & 1023, pxl = w2 >> 3, g = w2 & 7;
      uint4 vv = *(const uint4*)(smem + pl * 9216 + pxl * 72 + g * 8);
      ushort_t* dst = (pl ? sp1 : sp0) + ((size_t)(pxT * 128 + pxl)) * 256 + coT * 64 + g * 8;
      *(uint4*)dst = vv;
    }
  }
}

// ---------- 1x1 conv fp32 (to_z only) ----------
__global__ __launch_bounds__(256) void k_conv1x1(
    const float* __restrict__ in, float* __restrict__ out,
    const float* __restrict__ wT, const float* __restrict__ bias,
    int CI, int CO, int P)
{
  const int p = blockIdx.x * 256 + threadIdx.x;
  const int cob = blockIdx.y * 16;
  const int n = blockIdx.z;
  const float* inN = in + (size_t)n * CI * P + p;
  float acc[16];
#pragma unroll
  for (int i = 0; i < 16; ++i) acc[i] = bias[cob + i];
  const float* wr = wT + cob;
#pragma unroll 4
  for (int ci = 0; ci < CI; ++ci) {
    float iv = inN[(size_t)ci * P];
    const float* w = wr + (size_t)ci * CO;  // uniform
#pragma unroll
    for (int i = 0; i < 16; ++i) acc[i] = fmaf(iv, w[i], acc[i]);
  }
  float* outN = out + (size_t)n * CO * P + p;
#pragma unroll
  for (int i = 0; i < 16; ++i) outN[(size_t)(cob + i) * P] = acc[i];
}

// ---------- VQ partial: 16 chunks of 32 codes; per-j math identical ----------
__global__ __launch_bounds__(256) void k_vq_part(
    const float* __restrict__ z_e, const float* __restrict__ cb,
    const float* __restrict__ cnorm, float* __restrict__ pbest, int* __restrict__ pbid)
{
  int g = blockIdx.x * 256 + threadIdx.x;  // 8192 points
  int chunk = blockIdx.y;                  // 16 chunks
  int img = g >> 10, p = g & 1023;
  const float* zp = z_e + (size_t)img * 64 * 1024 + p;
  float z[64];
#pragma unroll
  for (int c = 0; c < 64; ++c) z[c] = zp[(size_t)c * 1024];
  float best = 3.4e38f; int bid = chunk << 5;
  const int j0 = chunk << 5;
  for (int j = j0; j < j0 + 32; ++j) {
    const float* cj = cb + j * 64;  // uniform -> scalar loads
    float m = 0.f;
#pragma unroll
    for (int c = 0; c < 64; ++c) m = fmaf(z[c], cj[c], m);
    float d = fmaf(-2.f, m, cnorm[j]);
    if (d < best) { best = d; bid = j; }  // strict <: first-min within chunk
  }
  pbest[chunk * 8192 + g] = best;
  pbid[chunk * 8192 + g] = bid;
}

// ---------- VQ reduce: argmin across chunks (ascending -> np.argmin) + e_k ----------
__global__ __launch_bounds__(256) void k_vq_reduce(
    const float* __restrict__ pbest, const int* __restrict__ pbid,
    const float* __restrict__ cb, float* __restrict__ ids_f, float* __restrict__ ek)
{
  int g = blockIdx.x * 256 + threadIdx.x;  // 8192
  float best = 3.4e38f; int bid = 0;
#pragma unroll
  for (int ch = 0; ch < 16; ++ch) {
    float d = pbest[ch * 8192 + g];
    int b = pbid[ch * 8192 + g];
    if (d < best) { best = d; bid = b; }
  }
  ids_f[g] = (float)bid;
  int img = g >> 10, p = g & 1023;
  const float* cbid = cb + bid * 64;
  float* ekp = ek + (size_t)img * 64 * 1024 + p;
#pragma unroll
  for (int c = 0; c < 64; ++c) ekp[(size_t)c * 1024] = cbid[c];
}

// ---------- from_z 1x1 (64->256) + relu -> NHWC bf16 ----------
__global__ __launch_bounds__(256) void k_from_z(
    const float* __restrict__ ek, ushort_t* __restrict__ nhwc,
    const float* __restrict__ wT, const float* __restrict__ bias)
{
  const int p = blockIdx.x * 256 + threadIdx.x;  // 0..1023
  const int co0 = blockIdx.y * 16;
  const int n = blockIdx.z;
  const float* inN = ek + (size_t)n * 64 * 1024 + p;
  float acc[16];
#pragma unroll
  for (int i = 0; i < 16; ++i) acc[i] = bias[co0 + i];
#pragma unroll 4
  for (int ci = 0; ci < 64; ++ci) {
    float iv = inN[(size_t)ci * 1024];
    const float* w = wT + (size_t)ci * 256 + co0;  // uniform
#pragma unroll
    for (int i = 0; i < 16; ++i) acc[i] = fmaf(iv, w[i], acc[i]);
  }
  uint pk[8];
#pragma unroll
  for (int i = 0; i < 8; ++i) {
    ushort_t lo = f2bf(fmaxf(acc[2 * i], 0.f));
    ushort_t hi = f2bf(fmaxf(acc[2 * i + 1], 0.f));
    pk[i] = (uint)lo | ((uint)hi << 16);
  }
  ushort_t* op = nhwc + (((size_t)n * 1024 + p) * 256 + co0);
  uint4 v0; v0.x = pk[0]; v0.y = pk[1]; v0.z = pk[2]; v0.w = pk[3];
  uint4 v1; v1.x = pk[4]; v1.y = pk[5]; v1.z = pk[6]; v1.w = pk[7];
  *(uint4*)(op) = v0;
  *(uint4*)(op + 8) = v1;
}

// ---------- t1 convtranspose 4x4 s2 p1, 256->256, bf16 MFMA, relu -> bf16 NHWC
__global__ __launch_bounds__(256) void k_mfma_t1(
    const ushort_t* __restrict__ nhwc, const ushort_t* __restrict__ wb,
    const float* __restrict__ bias, ushort_t* __restrict__ t1o)
{
  __shared__ ushort_t sA[128 * 32];
  __shared__ ushort_t sB[128 * 32];
  const int tid = threadIdx.x;
  const int lane = tid & 63;
  const int wv = tid >> 6;
  const int wm = wv & 1, wn = wv >> 1;
  const int l15 = lane & 15, q = lane >> 4;
  const int pxT = blockIdx.x, coT = blockIdx.y, par = blockIdx.z;
  const int ry = par & 1, rx = (par >> 1) & 1;
  const int pxbase = pxT * 128;
  const int img = pxbase >> 10;
  f32x4 acc[4][4];
#pragma unroll
  for (int i = 0; i < 4; ++i)
#pragma unroll
    for (int j = 0; j < 4; ++j) acc[i][j] = (f32x4){0.f, 0.f, 0.f, 0.f};

  for (int c = 0; c < 32; ++c) {
    const int tap = c >> 3, c8 = c & 7;
    const int a = tap >> 1, b = tap & 1;
    const ushort_t* Abase = wb + ((size_t)((par * 4 + tap) * 8 + c8) << 13);
#pragma unroll
    for (int r = 0; r < 2; ++r) {
      int idx = tid + 256 * r;
      int row = idx >> 2, kg = idx & 3;
      uint4 v = *(const uint4*)(Abase + ((coT * 128 + row) * 32 + kg * 8));
      *(uint4*)(&sA[row * 32 + kg * 8]) = v;
    }
#pragma unroll
    for (int r = 0; r < 2; ++r) {
      int idx = tid + 256 * r;
      int row = idx >> 2, kg = idx & 3;
      int px = pxbase + row;
      int u = (px >> 5) & 31, vv = px & 31;
      int iy = u + ry - a, ix = vv + rx - b;
      uint4 val;
      if ((unsigned)iy < 32u && (unsigned)ix < 32u) {
        val = *(const uint4*)(nhwc + ((size_t)(img * 1024 + iy * 32 + ix) * 256 + c8 * 32 + kg * 8));
      } else { val.x = 0u; val.y = 0u; val.z = 0u; val.w = 0u; }
      *(uint4*)(&sB[row * 32 + kg * 8]) = val;
    }
    __syncthreads();
    short8 af[4], bfr[4];
#pragma unroll
    for (int i = 0; i < 4; ++i)
      af[i] = *(const short8*)((const short*)sA + ((wm * 64 + i * 16 + l15) * 32 + q * 8));
#pragma unroll
    for (int j = 0; j < 4; ++j)
      bfr[j] = *(const short8*)((const short*)sB + ((wn * 64 + j * 16 + l15) * 32 + q * 8));
#pragma unroll
    for (int i = 0; i < 4; ++i)
#pragma unroll
      for (int j = 0; j < 4; ++j)
        acc[i][j] = __builtin_amdgcn_mfma_f32_16x16x32_bf16(af[i], bfr[j], acc[i][j], 0, 0, 0);
    __syncthreads();
  }
#pragma unroll
  for (int i = 0; i < 4; ++i) {
    int co = coT * 128 + wm * 64 + i * 16 + q * 4;
#pragma unroll
    for (int j = 0; j < 4; ++j) {
      int px = pxbase + wn * 64 + j * 16 + l15;
      int u = (px >> 5) & 31, vv = px & 31;
      int oy = 2 * u + ry, ox = 2 * vv + rx;
      ushort_t e0 = f2bf(fmaxf(acc[i][j][0] + bias[co + 0], 0.f));
      ushort_t e1 = f2bf(fmaxf(acc[i][j][1] + bias[co + 1], 0.f));
      ushort_t e2 = f2bf(fmaxf(acc[i][j][2] + bias[co + 2], 0.f));
      ushort_t e3 = f2bf(fmaxf(acc[i][j][3] + bias[co + 3], 0.f));
      uint2 pk; pk.x = (uint)e0 | ((uint)e1 << 16); pk.y = (uint)e2 | ((uint)e3 << 16);
      *(uint2*)(t1o + ((size_t)(img * 4096 + oy * 64 + ox) * 256 + co)) = pk;
    }
  }
}

// ---------- t2 convtranspose 4x4 s2 p1, 256->3, bf16 MFMA, sigmoid ----------
__global__ __launch_bounds__(256) void k_mfma_t2(
    const ushort_t* __restrict__ t1o, const ushort_t* __restrict__ wb,
    const float* __restrict__ bias, float* __restrict__ out)
{
  __shared__ ushort_t sA2[256 * 32];
  __shared__ ushort_t sB2[16 * 32];
  const int tid = threadIdx.x, lane = tid & 63, wv = tid >> 6;
  const int l15 = lane & 15, q = lane >> 4;
  const int pxb = blockIdx.x * 256;
  const int par = blockIdx.y;
  const int ry = par & 1, rx = (par >> 1) & 1;
  f32x4 acc[4];
#pragma unroll
  for (int m = 0; m < 4; ++m) acc[m] = (f32x4){0.f, 0.f, 0.f, 0.f};
  const int kg = tid & 3;
  size_t rb[4]; bool rv[4];
  for (int chunk = 0; chunk < 32; ++chunk) {
    const int tap = chunk >> 3, cg = chunk & 7;
    const int a = tap >> 1, b = tap & 1;
    if ((chunk & 7) == 0) {
#pragma unroll
      for (int i = 0; i < 4; ++i) {
        int row = (tid >> 2) + 64 * i;
        int px = pxb + row;
        int img = px >> 12, p = px & 4095, u = p >> 6, v = p & 63;
        int iy = u + ry - a, ix = v + rx - b;
        rv[i] = ((unsigned)iy < 64u) && ((unsigned)ix < 64u);
        rb[i] = ((size_t)(img * 4096 + iy * 64 + ix)) << 8;
      }
    }
    uint4 av[4];
#pragma unroll
    for (int i = 0; i < 4; ++i) {
      if (rv[i]) av[i] = *(const uint4*)(t1o + rb[i] + cg * 32 + kg * 8);
      else { av[i].x = 0; av[i].y = 0; av[i].z = 0; av[i].w = 0; }
    }
    uint4 bv;
    if (tid < 64) bv = *(const uint4*)(wb + ((size_t)(par * 32 + chunk)) * 512 + tid * 8);
    __syncthreads();
#pragma unroll
    for (int i = 0; i < 4; ++i)
      *(uint4*)(sA2 + ((tid >> 2) + 64 * i) * 32 + kg * 8) = av[i];
    if (tid < 64) *(uint4*)(sB2 + tid * 8) = bv;
    __syncthreads();
    short8 bf = *(const short8*)(sB2 + l15 * 32 + q * 8);
#pragma unroll
    for (int m = 0; m < 4; ++m) {
      short8 af = *(const short8*)(sA2 + (wv * 64 + m * 16 + l15) * 32 + q * 8);
      acc[m] = __builtin_amdgcn_mfma_f32_16x16x32_bf16(af, bf, acc[m], 0, 0, 0);
    }
    __syncthreads();
  }
  const int co = l15;
  if (co < 3) {
    float bco = bias[co];
#pragma unroll
    for (int m = 0; m < 4; ++m) {
#pragma unroll
      for (int r = 0; r < 4; ++r) {
        int px = pxb + wv * 64 + m * 16 + q * 4 + r;
        int img = px >> 12, p = px & 4095, u = p >> 6, v = p & 63;
        size_t addr = ((size_t)(img * 3 + co)) * 16384 + (2 * u + ry) * 128 + (2 * v + rx);
        out[addr] = 1.f / (1.f + expf(-(acc[m][r] + bco)));
      }
    }
  }
}

// ---------------------------------------------------------------------------
extern "C" void kernel_launch(void* const* d_in, const int* in_sizes, int n_in,
                              void* d_out, int out_size, void* d_ws, size_t ws_size,
                              hipStream_t stream) {
  (void)in_sizes; (void)n_in; (void)out_size; (void)ws_size;
  const float* x      = (const float*)d_in[0];
  const float* c1_w   = (const float*)d_in[1];
  const float* c1_b   = (const float*)d_in[2];
  const float* c2_w   = (const float*)d_in[3];
  const float* c2_b   = (const float*)d_in[4];
  const float* r0_w3  = (const float*)d_in[5];
  const float* r0_b3  = (const float*)d_in[6];
  const float* r0_w1  = (const float*)d_in[7];
  const float* r0_b1  = (const float*)d_in[8];
  const float* r1_w3  = (const float*)d_in[9];
  const float* r1_b3  = (const float*)d_in[10];
  const float* r1_w1  = (const float*)d_in[11];
  const float* r1_b1  = (const float*)d_in[12];
  const float* to_z_w = (const float*)d_in[13];
  const float* to_z_b = (const float*)d_in[14];
  const float* cb     = (const float*)d_in[15];
  const float* from_z_w = (const float*)d_in[16];
  const float* from_z_b = (const float*)d_in[17];
  const float* t1_w   = (const float*)d_in[18];
  const float* t1_b   = (const float*)d_in[19];
  const float* t2_w   = (const float*)d_in[20];
  const float* t2_b   = (const float*)d_in[21];

  float* wsf = (float*)d_ws;
  // era-overlapped regions (floats):
  ushort_t* xs1p0 = (ushort_t*)(wsf + 0);        // conv1-era [0, 4.2M)
  ushort_t* xs1p1 = (ushort_t*)(wsf + 4194304);  // conv1-era [4.2M, 8.4M)
  ushort_t* spB0  = (ushort_t*)(wsf + 0);        // res-era   [0, 1.05M)
  ushort_t* spB1  = (ushort_t*)(wsf + 1048576);  // res-era   [1.05M, 2.1M)
  float*    pbest = wsf + 0;                     // vq-era    [0, 131072)
  int*      pbid  = (int*)(wsf + 131072);        // vq-era
  float*    pr    = wsf + 2097152;               // res-era partial [2.1M, 4.2M)
  ushort_t* t1out = (ushort_t*)(wsf + 2097152);  // dec-era   [2.1M, 6.3M)
  ushort_t* decn  = (ushort_t*)(wsf + 6291456);  // dec-era   [6.3M, 7.3M)
  float*    h32   = wsf + 8388608;               // [8.4M, 10.5M)
  ushort_t* spA0  = (ushort_t*)(wsf + 10485760);
  ushort_t* spA1  = (ushort_t*)(wsf + 11534336);
  ushort_t* wp_c2   = (ushort_t*)(wsf + 12582912);
  ushort_t* wp_r0w3 = (ushort_t*)(wsf + 13631488);
  ushort_t* wp_r1w3 = (ushort_t*)(wsf + 14221312);
  ushort_t* wp_r0w1 = (ushort_t*)(wsf + 14811136);
  ushort_t* wp_r1w1 = (ushort_t*)(wsf + 14876672);
  float*    wt_c1   = wsf + 14942208;
  float*    wt_toz  = wsf + 14954496;
  float*    wt_fromz= wsf + 14970880;
  ushort_t* t1wb    = (ushort_t*)(wsf + 14987264);
  ushort_t* w2pk    = (ushort_t*)(wsf + 15511552);
  float*    cnorm   = wsf + 15544320;

  float* out_img = (float*)d_out;        // 393216
  float* z_e_out = out_img + 393216;     // 524288
  float* e_k_out = z_e_out + 524288;     // 524288
  float* ids_out = e_k_out + 524288;     // 8192 (stored as float)

  // ---- weight prep ----
  k_transpose_w<<<48, 256, 0, stream>>>(c1_w, wt_c1, 256, 48);
  k_transpose_w<<<64, 256, 0, stream>>>(to_z_w, wt_toz, 64, 256);
  k_transpose_w<<<64, 256, 0, stream>>>(from_z_w, wt_fromz, 256, 64);
  k_prep_enc<0><<<8192, 256, 0, stream>>>(c2_w,  wp_c2,   128 << 14);
  k_prep_enc<1><<<4608, 256, 0, stream>>>(r0_w3, wp_r0w3, 72 << 14);
  k_prep_enc<1><<<4608, 256, 0, stream>>>(r1_w3, wp_r1w3, 72 << 14);
  k_prep_enc<2><<<512,  256, 0, stream>>>(r0_w1, wp_r0w1, 8 << 14);
  k_prep_enc<2><<<512,  256, 0, stream>>>(r1_w1, wp_r1w1, 8 << 14);
  k_prep_t1w<<<4096, 256, 0, stream>>>(t1_w, t1wb);
  k_prep_t2w<<<256, 256, 0, stream>>>(t2_w, w2pk);
  k_prep_cb<<<2, 256, 0, stream>>>(cb, cnorm);

  // ---- encoder ----
  k_conv1_split<<<dim3(64, 4, 8), 256, 0, stream>>>(x, xs1p0, xs1p1, wt_c1, c1_b);
  // conv2 (split-K=2 -> partial in h32 region, then epilogue: relu, h32, splits)
  hipMemsetAsync(h32, 0, 8388608, stream);
  k_enc_mfma_split<0><<<dim3(64, 4, 2), 256, 0, stream>>>(xs1p0, xs1p1, wp_c2, h32);
  k_enc_epi<true><<<dim3(32, 16), 256, 0, stream>>>(h32, h32, spA0, spA1, c2_b);
  // r0 w3 (split-K=2 -> pr, epilogue: splits of relu)
  hipMemsetAsync(pr, 0, 8388608, stream);
  k_enc_mfma_split<1><<<dim3(64, 4, 2), 256, 0, stream>>>(spA0, spA1, wp_r0w3, pr);
  k_enc_epi<false><<<dim3(32, 16), 256, 0, stream>>>(pr, nullptr, spB0, spB1, r0_b3);
  // r0 w1: h += conv; write h32 + split(relu(h))
  k_enc_mfma<2, true,  false, true,  true ><<<dim3(64, 4), 256, 0, stream>>>(
      spB0, spB1, wp_r0w1, r0_b1, h32, spA0, spA1);
  // r1 w3 (split-K=2)
  hipMemsetAsync(pr, 0, 8388608, stream);
  k_enc_mfma_split<1><<<dim3(64, 4, 2), 256, 0, stream>>>(spA0, spA1, wp_r1w3, pr);
  k_enc_epi<false><<<dim3(32, 16), 256, 0, stream>>>(pr, nullptr, spB0, spB1, r1_b3);
  // r1 w1: h += conv; write h32 only
  k_enc_mfma<2, true,  false, true,  false><<<dim3(64, 4), 256, 0, stream>>>(
      spB0, spB1, wp_r1w1, r1_b1, h32, nullptr, nullptr);
  // to_z (fp32)
  k_conv1x1<<<dim3(4, 4, 8), 256, 0, stream>>>(h32, z_e_out, wt_toz, to_z_b, 256, 64, 1024);

  // ---- VQ (chunk-parallel; bit-identical argmin) ----
  k_vq_part<<<dim3(32, 16), 256, 0, stream>>>(z_e_out, cb, cnorm, pbest, pbid);
  k_vq_reduce<<<32, 256, 0, stream>>>(pbest, pbid, cb, ids_out, e_k_out);

  // ---- decoder (bf16) ----
  k_from_z<<<dim3(4, 16, 8), 256, 0, stream>>>(e_k_out, decn, wt_fromz, from_z_b);
  k_mfma_t1<<<dim3(64, 2, 4), 256, 0, stream>>>(decn, t1wb, t1_b, t1out);
  k_mfma_t2<<<dim3(128, 4), 256, 0, stream>>>(t1out, w2pk, t2_b, out_img);
}